// Round 1
// baseline (31224.445 us; speedup 1.0000x reference)
//
#include <hip/hip_runtime.h>
#include <hip/hip_bf16.h>

#define B_   64
#define S_   512
#define I_   512
#define H_   1024
#define G4H  4096
#define O_   512
#define CH_  32    // timesteps per chunk
#define NCH  (S_ / CH_)   // 16 chunks per layer

#define NBLK   512        // chunk_k grid (2 blocks/CU on 256 CUs)
#define BARSTR 32         // uints per barrier counter (128B pad, own cacheline)

typedef short s16x8 __attribute__((ext_vector_type(8)));
typedef short s16x4 __attribute__((ext_vector_type(4)));
typedef float f32x4 __attribute__((ext_vector_type(4)));
using bf16 = __hip_bfloat16;

__device__ __forceinline__ float bf2f(bf16 v) { return __bfloat162float(v); }
__device__ __forceinline__ bf16  f2bf(float f) { return __float2bfloat16(f); }
__device__ __forceinline__ short f2bfb(float f) { bf16 h = __float2bfloat16(f); return *(short*)&h; }

__device__ __forceinline__ void storeC(float* p, float v) { *p = v; }
__device__ __forceinline__ void storeC(bf16* p, float v)  { *p = f2bf(v); }

// ---------------------------------------------------------------------------
// C = A @ Bw^T (+bias1+bias2). Bw fp32 global (bf16-converted while staging).
// A is fp32 (ABF=0) or bf16 (ABF=1). fp32 MFMA accum; C bf16 or fp32 (CT).
// AMAP 0: a_row = m                            (chunk layout [t][b] rows)
// AMAP 1: a_row = (m&63)*S + t0 + (m>>6)       (gather from x [B][S][I])
// CMAP 0: c_row = m
// CMAP 2: c_row = (m&63)*S + t0 + (m>>6)       (scatter to out [B*S][O])
// Tile 128x128, BK=32, 256 threads (4 waves, 64x64 quadrant each).
// ---------------------------------------------------------------------------
template <int AMAP, int CMAP, int ABF, typename CT>
__global__ __launch_bounds__(256) void gemm_bt(
    const void* __restrict__ Av, const float* __restrict__ Bw,
    CT* __restrict__ C,
    const float* __restrict__ bias1, const float* __restrict__ bias2,
    int M, int N, int K, int t0)
{
    __shared__ bf16 As[128 * 40];
    __shared__ bf16 Bs[128 * 40];

    const int tid  = threadIdx.x;
    const int wave = tid >> 6;
    const int lane = tid & 63;
    const int quad = lane >> 4;
    const int l16  = lane & 15;

    const int m_base = blockIdx.x * 128;
    const int n_base = blockIdx.y * 128;
    const int wm = (wave >> 1) * 64;
    const int wn = (wave & 1) * 64;

    f32x4 acc[4][4] = {};

    for (int k0 = 0; k0 < K; k0 += 32) {
        __syncthreads();
#pragma unroll
        for (int i = 0; i < 2; i++) {
            int l   = tid + i * 256;     // 0..511
            int row = l >> 2;            // 0..127
            int ko  = (l & 3) * 8;       // 0,8,16,24
            int m   = m_base + row;
            long ar = m;
            if (AMAP == 1) ar = (long)(m & 63) * S_ + t0 + (m >> 6);

            if (ABF) {
                const bf16* ap = (const bf16*)Av + ar * (long)K + k0 + ko;
                *(s16x8*)(&As[row * 40 + ko]) = *(const s16x8*)ap;
            } else {
                const float* ap = (const float*)Av + ar * (long)K + k0 + ko;
                f32x4 a0 = *(const f32x4*)ap;
                f32x4 a1 = *(const f32x4*)(ap + 4);
                s16x8 av;
#pragma unroll
                for (int j = 0; j < 4; j++) { av[j] = f2bfb(a0[j]); av[4 + j] = f2bfb(a1[j]); }
                *(s16x8*)(&As[row * 40 + ko]) = av;
            }

            const float* bp = &Bw[(long)(n_base + row) * K + k0 + ko];
            f32x4 b0 = *(const f32x4*)bp;
            f32x4 b1 = *(const f32x4*)(bp + 4);
            s16x8 bv;
#pragma unroll
            for (int j = 0; j < 4; j++) { bv[j] = f2bfb(b0[j]); bv[4 + j] = f2bfb(b1[j]); }
            *(s16x8*)(&Bs[row * 40 + ko]) = bv;
        }
        __syncthreads();

        s16x8 af[4], bfr[4];
#pragma unroll
        for (int i = 0; i < 4; i++)
            af[i] = *(const s16x8*)(&As[(wm + i * 16 + l16) * 40 + quad * 8]);
#pragma unroll
        for (int j = 0; j < 4; j++)
            bfr[j] = *(const s16x8*)(&Bs[(wn + j * 16 + l16) * 40 + quad * 8]);
#pragma unroll
        for (int i = 0; i < 4; i++)
#pragma unroll
            for (int j = 0; j < 4; j++)
                acc[i][j] = __builtin_amdgcn_mfma_f32_16x16x32_bf16(af[i], bfr[j], acc[i][j], 0, 0, 0);
    }

    // C/D layout: col = lane&15, row = (lane>>4)*4 + reg
#pragma unroll
    for (int i = 0; i < 4; i++) {
#pragma unroll
        for (int j = 0; j < 4; j++) {
#pragma unroll
            for (int r = 0; r < 4; r++) {
                int m = m_base + wm + i * 16 + quad * 4 + r;
                int n = n_base + wn + j * 16 + l16;
                float v = acc[i][j][r];
                if (bias1) v += bias1[n];
                if (bias2) v += bias2[n];
                long cr = m;
                if (CMAP == 2) cr = (long)(m & 63) * S_ + t0 + (m >> 6);
                storeC(&C[cr * (long)N + n], v);
            }
        }
    }
}

// ---------------------------------------------------------------------------
// Device-wide barrier. One counter per step (monotonic, pre-zeroed, never
// reset within a launch sequence -> no sense reversal). Release fence before
// arrive, acquire fence after observe; composition with __syncthreads gives
// the same cross-XCD visibility the old per-step kernel boundary provided.
// Co-residency of all NBLK blocks is guaranteed by the cooperative launch.
// ---------------------------------------------------------------------------
__device__ __forceinline__ void grid_bar(unsigned* ctr)
{
    __syncthreads();                       // all waves' stores drained (vmcnt0) + block-fence
    if (threadIdx.x == 0) {
        __threadfence();                   // agent-scope release (L2 writeback)
        __hip_atomic_fetch_add(ctr, 1u, __ATOMIC_RELAXED, __HIP_MEMORY_SCOPE_AGENT);
        while (__hip_atomic_load(ctr, __ATOMIC_RELAXED, __HIP_MEMORY_SCOPE_AGENT) < NBLK)
            __builtin_amdgcn_s_sleep(1);
        __threadfence();                   // agent-scope acquire (L1/L2 invalidate)
    }
    __syncthreads();
}

// ---------------------------------------------------------------------------
// Persistent per-chunk recurrence: ONE cooperative launch runs all CH_ steps
// for layer0 (chunk cpar) and layer1 (chunk cpar-1) with grid_bar between
// steps. Whh slice staged into LDS ONCE per chunk (was: per step). c-state
// held in a register for the whole chunk (thread->(batch,unit) mapping is
// step-invariant). Inactive-layer blocks still arrive at every barrier.
// blocks [0,256) -> layer 0 (iff do0); [256,512) -> layer 1 (iff do1).
// ---------------------------------------------------------------------------
__global__ __launch_bounds__(256) void chunk_k(
    const bf16* __restrict__ xg0,  // [CH][B][4H] layer-0 input contrib, chunk cpar
    const bf16* __restrict__ xg1,  // [CH][B][4H] layer-1 input contrib, chunk cpar-1
    const float* __restrict__ Whh0,
    const float* __restrict__ Whh1,
    bf16* __restrict__ h0w,        // [2][CH+1][B][H] double-buffered window
    bf16* __restrict__ h1w,        // [CH+1][B][H]
    float* __restrict__ c0,
    float* __restrict__ c1,
    unsigned* __restrict__ bar,    // [CH][BARSTR] counters for this launch, pre-zeroed
    int cpar, int do0, int do1)
{
    const int layer  = blockIdx.x >> 8;
    const int nb     = blockIdx.x & 255;
    const int active = layer ? do1 : do0;   // block-uniform

    const bf16*  xg  = layer ? xg1  : xg0;
    const float* Whh = layer ? Whh1 : Whh0;
    float*       cst = layer ? c1   : c0;

    bf16 *rbuf, *cbuf;
    if (layer == 0) {
        rbuf = h0w + (size_t)(cpar & 1) * (CH_ + 1) * B_ * H_;
        cbuf = h0w + (size_t)((cpar + 1) & 1) * (CH_ + 1) * B_ * H_;
    } else {
        rbuf = h1w; cbuf = h1w;
    }

    const int tid  = threadIdx.x;
    const int lane = tid & 63;
    const int wave = tid >> 6;
    const int quad = lane >> 4;
    const int l16  = lane & 15;

    __shared__ bf16 wsh[16][1032];   // 33 KB; +8 pad: 2-way aliasing only (free)
    __shared__ float gs[64][17];     // 4.3 KB

    // stage Whh slice (16 gate-rows x 1024) fp32 -> bf16 LDS, ONCE per chunk
    if (active) {
        int r  = tid >> 4;                 // 0..15
        int cc = (tid & 15) * 64;          // 64 elems per thread
        long jrow = (long)(r >> 2) * H_ + nb * 4 + (r & 3);
        const float* src = Whh + jrow * H_ + cc;
#pragma unroll
        for (int q = 0; q < 64; q += 4) {
            f32x4 v = *(const f32x4*)(src + q);
            s16x4 o;
#pragma unroll
            for (int w = 0; w < 4; w++) o[w] = f2bfb(v[w]);
            *(s16x4*)(&wsh[r][cc + q]) = o;
        }
    }
    __syncthreads();

    // c-state in a register for the whole chunk
    const int u    = tid & 3;
    const int bb   = tid >> 2;
    const int unit = nb * 4 + u;
    float creg = active ? cst[(long)bb * H_ + unit] : 0.f;

    const int jcol = (l16 >> 2) * H_ + nb * 4 + (l16 & 3);

    for (int j = 0; j < CH_; j++) {
        if (active) {
            // issue xg loads early; latency hides under the MFMA loop
            const bf16* xgt = xg + (long)j * (B_ * G4H);
            float xv[4];
#pragma unroll
            for (int r = 0; r < 4; r++)
                xv[r] = bf2f(xgt[(long)(wave * 16 + quad * 4 + r) * G4H + jcol]);

            const bf16* aptr = rbuf + (long)j * (B_ * H_)
                             + (long)(wave * 16 + l16) * H_ + quad * 8;
            f32x4 acc = {};
#pragma unroll 8
            for (int k = 0; k < H_; k += 32) {
                s16x8 a = *(const s16x8*)(aptr + k);
                s16x8 b = *(const s16x8*)(&wsh[l16][k + quad * 8]);
                acc = __builtin_amdgcn_mfma_f32_16x16x32_bf16(a, b, acc, 0, 0, 0);
            }
#pragma unroll
            for (int r = 0; r < 4; r++)
                gs[wave * 16 + quad * 4 + r][l16] = acc[r] + xv[r];
        }
        __syncthreads();

        if (active) {
            float gi = gs[bb][0 + u];
            float gf = gs[bb][4 + u];
            float gg = gs[bb][8 + u];
            float go = gs[bb][12 + u];

            float ig = 1.f / (1.f + __expf(-gi));
            float fg = 1.f / (1.f + __expf(-gf));
            float og = 1.f / (1.f + __expf(-go));
            float e2 = __expf(-2.f * fabsf(gg));
            float tg = (1.f - e2) / (1.f + e2);
            tg = (gg < 0.f) ? -tg : tg;

            creg = fg * creg + ig * tg;
            float e2c = __expf(-2.f * fabsf(creg));
            float tc = (1.f - e2c) / (1.f + e2c);
            tc = (creg < 0.f) ? -tc : tc;

            bf16 hv = f2bf(og * tc);
            rbuf[(long)(j + 1) * (B_ * H_) + (long)bb * H_ + unit] = hv;
            if (j == CH_ - 1)
                cbuf[(long)bb * H_ + unit] = hv;   // carry to next window's slot 0
        }

        // inter-step device barrier (skip after last step: kernel boundary covers it)
        if (j < CH_ - 1)
            grid_bar(bar + (size_t)j * BARSTR);
    }

    if (active) cst[(long)bb * H_ + unit] = creg;
}

// zero c-states, carry-in h slots, and barrier counters
__global__ __launch_bounds__(256) void init_k(
    float* c0, float* c1, bf16* h0w, bf16* h1w, unsigned* bar, int nbar)
{
    int i = blockIdx.x * 256 + threadIdx.x;
    if (i < B_ * H_) {
        c0[i] = 0.f; c1[i] = 0.f;
        h0w[i] = f2bf(0.f);   // buf 0, slot 0
        h1w[i] = f2bf(0.f);   // slot 0
    }
    if (i < nbar) bar[i] = 0u;
}

// h_n: layer0 = h0w buf0 slot0 (final carry), layer1 = h1w slot0. c_n fp32.
__global__ __launch_bounds__(256) void finalize_k(
    const bf16* __restrict__ h0w, const bf16* __restrict__ h1w,
    const float* __restrict__ c0, const float* __restrict__ c1,
    float* __restrict__ out_hn, float* __restrict__ out_cn)
{
    int i = blockIdx.x * 256 + threadIdx.x;
    if (i < B_ * H_) {
        out_hn[i]            = bf2f(h0w[i]);
        out_hn[B_ * H_ + i]  = bf2f(h1w[i]);
        out_cn[i]            = c0[i];
        out_cn[B_ * H_ + i]  = c1[i];
    }
}

extern "C" void kernel_launch(void* const* d_in, const int* in_sizes, int n_in,
                              void* d_out, int out_size, void* d_ws, size_t ws_size,
                              hipStream_t stream)
{
    const float* x    = (const float*)d_in[0];
    const float* Wih0 = (const float*)d_in[1];
    const float* Whh0 = (const float*)d_in[2];
    const float* bih0 = (const float*)d_in[3];
    const float* bhh0 = (const float*)d_in[4];
    const float* Wih1 = (const float*)d_in[5];
    const float* Whh1 = (const float*)d_in[6];
    const float* bih1 = (const float*)d_in[7];
    const float* bhh1 = (const float*)d_in[8];
    const float* Wfc  = (const float*)d_in[9];
    const float* bfc  = (const float*)d_in[10];
    float* out = (float*)d_out;

    // workspace (~45 MB + 70 KB barriers)
    char* p = (char*)d_ws;
    float* c0  = (float*)p; p += (size_t)B_ * H_ * 4;                       // 256 KB
    float* c1  = (float*)p; p += (size_t)B_ * H_ * 4;                       // 256 KB
    bf16* h0w  = (bf16*)p;  p += (size_t)2 * (CH_ + 1) * B_ * H_ * 2;       // 8.25 MB
    bf16* h1w  = (bf16*)p;  p += (size_t)(CH_ + 1) * B_ * H_ * 2;           // 4.13 MB
    bf16* xg0  = (bf16*)p;  p += (size_t)CH_ * B_ * G4H * 2;                // 16 MB
    bf16* xg1  = (bf16*)p;  p += (size_t)CH_ * B_ * G4H * 2;                // 16 MB
    unsigned* bar = (unsigned*)p; p += (size_t)(NCH + 1) * CH_ * BARSTR * 4;// 70 KB

    const int nbar = (NCH + 1) * CH_ * BARSTR;
    init_k<<<(B_ * H_ + 255) / 256, 256, 0, stream>>>(c0, c1, h0w, h1w, bar, nbar);

    const dim3 gxg0((B_ * CH_) / 128, G4H / 128);  // 16 x 32
    const dim3 gfc((B_ * CH_) / 128, O_ / 128);    // 16 x 4

    // Diagonal pipeline over 17 groups: layer0 on chunk c, layer1 on chunk c-1.
    for (int c = 0; c <= NCH; c++) {
        const int do0 = (c < NCH);
        const int do1 = (c >= 1);

        if (do0) {
            // xg0(c): xg0[t][b] = x[b][c*CH+t] @ Wih0^T + bih0 + bhh0   (A fp32)
            gemm_bt<1, 0, 0, bf16><<<gxg0, 256, 0, stream>>>(
                x, Wih0, xg0, bih0, bhh0, B_ * CH_, G4H, I_, c * CH_);
        }
        if (do1) {
            // xg1(c-1): from h0 window buf (c-1)&1, slots 1..CH           (A bf16)
            const bf16* h0chunk = h0w + (size_t)((c - 1) & 1) * (CH_ + 1) * B_ * H_ + B_ * H_;
            gemm_bt<0, 0, 1, bf16><<<gxg0, 256, 0, stream>>>(
                h0chunk, Wih1, xg1, bih1, bhh1, B_ * CH_, G4H, H_, 0);
        }

        // one persistent cooperative launch = all CH_ steps of this group
        {
            const bf16*  a0  = xg0;  const bf16*  a1  = xg1;
            const float* w0  = Whh0; const float* w1  = Whh1;
            bf16* hp0 = h0w; bf16* hp1 = h1w;
            float* cp0 = c0; float* cp1 = c1;
            unsigned* bp = bar + (size_t)c * CH_ * BARSTR;
            int cv = c, d0 = do0, d1 = do1;
            void* args[] = { &a0, &a1, &w0, &w1, &hp0, &hp1,
                             &cp0, &cp1, &bp, &cv, &d0, &d1 };
            hipLaunchCooperativeKernel((const void*)chunk_k,
                                       dim3(NBLK), dim3(256), args, 0, stream);
        }

        if (do1) {
            // FC on layer-1 chunk c-1: out rows t0=(c-1)*CH              (A bf16, C fp32)
            gemm_bt<0, 2, 1, float><<<gfc, 256, 0, stream>>>(
                h1w + B_ * H_, Wfc, out, bfc, (const float*)nullptr,
                B_ * CH_, O_, H_, (c - 1) * CH_);
        }
    }

    finalize_k<<<(B_ * H_ + 255) / 256, 256, 0, stream>>>(
        h0w, h1w, c0, c1,
        out + (size_t)B_ * S_ * O_,
        out + (size_t)B_ * S_ * O_ + 2 * (size_t)B_ * H_);
}

// Round 2
// 10441.045 us; speedup vs baseline: 2.9905x; 2.9905x over previous
//
#include <hip/hip_runtime.h>
#include <hip/hip_bf16.h>

#define B_   64
#define S_   512
#define I_   512
#define H_   1024
#define G4H  4096
#define O_   512
#define CH_  32    // timesteps per chunk
#define NCH  (S_ / CH_)   // 16 chunks per layer

#define NBLK   256        // chunk_k grid: 128 blocks/layer (Ng=32 gate-cols each)
#define BARSTR 32         // uints per barrier counter (128B pad, own cacheline)

typedef short s16x8 __attribute__((ext_vector_type(8)));
typedef short s16x4 __attribute__((ext_vector_type(4)));
typedef float f32x4 __attribute__((ext_vector_type(4)));
typedef unsigned long long u64;
using bf16 = __hip_bfloat16;

__device__ __forceinline__ float bf2f(bf16 v) { return __bfloat162float(v); }
__device__ __forceinline__ bf16  f2bf(float f) { return __float2bfloat16(f); }
__device__ __forceinline__ short f2bfb(float f) { bf16 h = __float2bfloat16(f); return *(short*)&h; }

__device__ __forceinline__ void storeC(float* p, float v) { *p = v; }
__device__ __forceinline__ void storeC(bf16* p, float v)  { *p = f2bf(v); }

// ---------------------------------------------------------------------------
// C = A @ Bw^T (+bias1+bias2). Bw fp32 global (bf16-converted while staging).
// Tile 128x128, BK=32, 256 threads (4 waves, 64x64 quadrant each).
// ---------------------------------------------------------------------------
template <int AMAP, int CMAP, int ABF, typename CT>
__global__ __launch_bounds__(256) void gemm_bt(
    const void* __restrict__ Av, const float* __restrict__ Bw,
    CT* __restrict__ C,
    const float* __restrict__ bias1, const float* __restrict__ bias2,
    int M, int N, int K, int t0)
{
    __shared__ bf16 As[128 * 40];
    __shared__ bf16 Bs[128 * 40];

    const int tid  = threadIdx.x;
    const int wave = tid >> 6;
    const int lane = tid & 63;
    const int quad = lane >> 4;
    const int l16  = lane & 15;

    const int m_base = blockIdx.x * 128;
    const int n_base = blockIdx.y * 128;
    const int wm = (wave >> 1) * 64;
    const int wn = (wave & 1) * 64;

    f32x4 acc[4][4] = {};

    for (int k0 = 0; k0 < K; k0 += 32) {
        __syncthreads();
#pragma unroll
        for (int i = 0; i < 2; i++) {
            int l   = tid + i * 256;     // 0..511
            int row = l >> 2;            // 0..127
            int ko  = (l & 3) * 8;       // 0,8,16,24
            int m   = m_base + row;
            long ar = m;
            if (AMAP == 1) ar = (long)(m & 63) * S_ + t0 + (m >> 6);

            if (ABF) {
                const bf16* ap = (const bf16*)Av + ar * (long)K + k0 + ko;
                *(s16x8*)(&As[row * 40 + ko]) = *(const s16x8*)ap;
            } else {
                const float* ap = (const float*)Av + ar * (long)K + k0 + ko;
                f32x4 a0 = *(const f32x4*)ap;
                f32x4 a1 = *(const f32x4*)(ap + 4);
                s16x8 av;
#pragma unroll
                for (int j = 0; j < 4; j++) { av[j] = f2bfb(a0[j]); av[4 + j] = f2bfb(a1[j]); }
                *(s16x8*)(&As[row * 40 + ko]) = av;
            }

            const float* bp = &Bw[(long)(n_base + row) * K + k0 + ko];
            f32x4 b0 = *(const f32x4*)bp;
            f32x4 b1 = *(const f32x4*)(bp + 4);
            s16x8 bv;
#pragma unroll
            for (int j = 0; j < 4; j++) { bv[j] = f2bfb(b0[j]); bv[4 + j] = f2bfb(b1[j]); }
            *(s16x8*)(&Bs[row * 40 + ko]) = bv;
        }
        __syncthreads();

        s16x8 af[4], bfr[4];
#pragma unroll
        for (int i = 0; i < 4; i++)
            af[i] = *(const s16x8*)(&As[(wm + i * 16 + l16) * 40 + quad * 8]);
#pragma unroll
        for (int j = 0; j < 4; j++)
            bfr[j] = *(const s16x8*)(&Bs[(wn + j * 16 + l16) * 40 + quad * 8]);
#pragma unroll
        for (int i = 0; i < 4; i++)
#pragma unroll
            for (int j = 0; j < 4; j++)
                acc[i][j] = __builtin_amdgcn_mfma_f32_16x16x32_bf16(af[i], bfr[j], acc[i][j], 0, 0, 0);
    }

    // C/D layout: col = lane&15, row = (lane>>4)*4 + reg
#pragma unroll
    for (int i = 0; i < 4; i++) {
#pragma unroll
        for (int j = 0; j < 4; j++) {
#pragma unroll
            for (int r = 0; r < 4; r++) {
                int m = m_base + wm + i * 16 + quad * 4 + r;
                int n = n_base + wn + j * 16 + l16;
                float v = acc[i][j][r];
                if (bias1) v += bias1[n];
                if (bias2) v += bias2[n];
                long cr = m;
                if (CMAP == 2) cr = (long)(m & 63) * S_ + t0 + (m >> 6);
                storeC(&C[cr * (long)N + n], v);
            }
        }
    }
}

// ---------------------------------------------------------------------------
// Fence-free device barrier. All cross-block-mutable data (h window) moves via
// agent-scope RELAXED atomics (sc1: bypass non-coherent per-XCD L2, complete
// at the coherent point). __syncthreads drains each wave's stores (vmcnt ack
// from the coherent point); the arrive-add is issued after that, so a poller
// observing ctr==NBLK is ordered after all h-stores. No buffer_wbl2/inv.
// Counters are monotonic, per-step, pre-zeroed (no sense reversal).
// ---------------------------------------------------------------------------
__device__ __forceinline__ void grid_bar(unsigned* ctr)
{
    __syncthreads();
    if (threadIdx.x == 0) {
        __hip_atomic_fetch_add(ctr, 1u, __ATOMIC_RELAXED, __HIP_MEMORY_SCOPE_AGENT);
        while (__hip_atomic_load(ctr, __ATOMIC_RELAXED, __HIP_MEMORY_SCOPE_AGENT) < NBLK)
            __builtin_amdgcn_s_sleep(1);
    }
    __syncthreads();
}

// ---------------------------------------------------------------------------
// Persistent per-chunk recurrence. 256 blocks: [0,128) layer 0 (iff do0),
// [128,256) layer 1 (iff do1). Each block owns 8 hidden units = 32 gate-cols.
// Whh slice (32 x 1024) staged fp32->bf16 in LDS once per chunk; c-state in
// registers for the whole chunk. h window accessed with agent-scope relaxed
// atomics (8B loads grouped 16-at-a-time so issue pipelines; 4B paired
// stores). Inter-step sync = grid_bar (fence-free).
// ---------------------------------------------------------------------------
__global__ __launch_bounds__(256) void chunk_k(
    const bf16* __restrict__ xg0,  // [CH][B][4H] layer-0 input contrib, chunk cpar
    const bf16* __restrict__ xg1,  // [CH][B][4H] layer-1 input contrib, chunk cpar-1
    const float* __restrict__ Whh0,
    const float* __restrict__ Whh1,
    bf16* __restrict__ h0w,        // [2][CH+1][B][H] double-buffered window
    bf16* __restrict__ h1w,        // [CH+1][B][H]
    float* __restrict__ c0,
    float* __restrict__ c1,
    unsigned* __restrict__ bar,    // [CH][BARSTR] counters, pre-zeroed
    int cpar, int do0, int do1)
{
    const int layer  = blockIdx.x >> 7;
    const int nb     = blockIdx.x & 127;
    const int active = layer ? do1 : do0;   // block-uniform

    const bf16*  xg  = layer ? xg1  : xg0;
    const float* Whh = layer ? Whh1 : Whh0;
    float*       cst = layer ? c1   : c0;

    bf16 *rbuf, *cbuf;
    if (layer == 0) {
        rbuf = h0w + (size_t)(cpar & 1) * (CH_ + 1) * B_ * H_;
        cbuf = h0w + (size_t)((cpar + 1) & 1) * (CH_ + 1) * B_ * H_;
    } else {
        rbuf = h1w; cbuf = h1w;
    }

    const int tid  = threadIdx.x;
    const int lane = tid & 63;
    const int wave = tid >> 6;
    const int quad = lane >> 4;
    const int l16  = lane & 15;

    __shared__ bf16  wsh[32][1032];  // 66 KB; +8 pad: 2-way aliasing only (free)
    __shared__ float gs[64][36];     // 9.2 KB; stride 36: 2-way max on reads

    // stage Whh slice (32 gate-rows x 1024) fp32 -> bf16 LDS, ONCE per chunk.
    // row r <-> Whh row (r>>3)*H + nb*8 + (r&7)   (gate g = r>>3, unit uu = r&7)
    if (active) {
        int r  = tid >> 3;                 // 0..31
        int cc = (tid & 7) * 128;          // 128 elems per thread
        const float* src = Whh + ((long)(r >> 3) * H_ + nb * 8 + (r & 7)) * H_ + cc;
#pragma unroll
        for (int q = 0; q < 128; q += 4) {
            f32x4 v = *(const f32x4*)(src + q);
            s16x4 o;
#pragma unroll
            for (int w = 0; w < 4; w++) o[w] = f2bfb(v[w]);
            *(s16x4*)(&wsh[r][cc + q]) = o;
        }
    }
    __syncthreads();

    // c-state in registers for the whole chunk: cell = tid + rep*256,
    // bb = cell>>3 (batch), uu = cell&7 (unit within block)
    float creg[2];
#pragma unroll
    for (int rep = 0; rep < 2; rep++) {
        int cell = tid + rep * 256;
        creg[rep] = active ? cst[(long)(cell >> 3) * H_ + nb * 8 + (cell & 7)] : 0.f;
    }

    for (int j = 0; j < CH_; j++) {
        if (active) {
            // xg gather for this step's epilogue (issued early, hides under MFMA)
            const bf16* xgt = xg + (long)j * (B_ * G4H);
            float xv0[4], xv1[4];
#pragma unroll
            for (int r = 0; r < 4; r++) {
                int m   = wave * 16 + quad * 4 + r;
                int c0i = l16;
                int c1i = 16 + l16;
                xv0[r] = bf2f(xgt[(long)m * G4H + (long)(c0i >> 3) * H_ + nb * 8 + (c0i & 7)]);
                xv1[r] = bf2f(xgt[(long)m * G4H + (long)(c1i >> 3) * H_ + nb * 8 + (c1i & 7)]);
            }

            // h(t) @ Whh_slice^T : M=64 x N=32, K=1024. a-row = wave*16+l16.
            // a from global via agent-relaxed 8B atomics (coherent, no fence).
            const u64* ap = (const u64*)(rbuf + (long)j * (B_ * H_)
                           + (long)(wave * 16 + l16) * H_) + quad * 2;
            f32x4 acc0 = {}, acc1 = {};
#pragma unroll
            for (int g = 0; g < 4; g++) {
                u64 lo[8], hi[8];
#pragma unroll
                for (int t = 0; t < 8; t++) {
                    u64* p = (u64*)(ap + (size_t)(g * 8 + t) * 8);
                    lo[t] = __hip_atomic_load(p,     __ATOMIC_RELAXED, __HIP_MEMORY_SCOPE_AGENT);
                    hi[t] = __hip_atomic_load(p + 1, __ATOMIC_RELAXED, __HIP_MEMORY_SCOPE_AGENT);
                }
#pragma unroll
                for (int t = 0; t < 8; t++) {
                    int k = (g * 8 + t) * 32;
                    union { u64 q[2]; s16x8 v; } ua;
                    ua.q[0] = lo[t]; ua.q[1] = hi[t];
                    s16x8 b0 = *(const s16x8*)(&wsh[l16][k + quad * 8]);
                    s16x8 b1 = *(const s16x8*)(&wsh[16 + l16][k + quad * 8]);
                    acc0 = __builtin_amdgcn_mfma_f32_16x16x32_bf16(ua.v, b0, acc0, 0, 0, 0);
                    acc1 = __builtin_amdgcn_mfma_f32_16x16x32_bf16(ua.v, b1, acc1, 0, 0, 0);
                }
            }

            // C layout: col = l16 (+16 for frag1), row = quad*4 + reg
#pragma unroll
            for (int r = 0; r < 4; r++) {
                int m = wave * 16 + quad * 4 + r;
                gs[m][l16]      = acc0[r] + xv0[r];
                gs[m][16 + l16] = acc1[r] + xv1[r];
            }
        }
        __syncthreads();

        if (active) {
            unsigned short hb[2];
#pragma unroll
            for (int rep = 0; rep < 2; rep++) {
                int cell = tid + rep * 256;
                int bb = cell >> 3, uu = cell & 7;
                float gi = gs[bb][uu];
                float gf = gs[bb][8 + uu];
                float gg = gs[bb][16 + uu];
                float go = gs[bb][24 + uu];

                float ig = 1.f / (1.f + __expf(-gi));
                float fg = 1.f / (1.f + __expf(-gf));
                float og = 1.f / (1.f + __expf(-go));
                float e2 = __expf(-2.f * fabsf(gg));
                float tg = (1.f - e2) / (1.f + e2);
                tg = (gg < 0.f) ? -tg : tg;

                creg[rep] = fg * creg[rep] + ig * tg;
                float e2c = __expf(-2.f * fabsf(creg[rep]));
                float tc = (1.f - e2c) / (1.f + e2c);
                tc = (creg[rep] < 0.f) ? -tc : tc;

                bf16 hv = f2bf(og * tc);
                hb[rep] = *(unsigned short*)&hv;
            }
            // pair adjacent units via shfl -> 4B agent-relaxed stores
#pragma unroll
            for (int rep = 0; rep < 2; rep++) {
                int cell = tid + rep * 256;
                int bb = cell >> 3, uu = cell & 7;
                unsigned my    = hb[rep];
                unsigned other = (unsigned)__shfl((int)my, lane ^ 1, 64);
                if (!(uu & 1)) {
                    unsigned v32 = my | (other << 16);
                    unsigned* dst = (unsigned*)(rbuf + (long)(j + 1) * (B_ * H_)
                                    + (long)bb * H_ + nb * 8 + uu);
                    __hip_atomic_store(dst, v32, __ATOMIC_RELAXED, __HIP_MEMORY_SCOPE_AGENT);
                    if (j == CH_ - 1) {
                        unsigned* cd = (unsigned*)(cbuf + (long)bb * H_ + nb * 8 + uu);
                        __hip_atomic_store(cd, v32, __ATOMIC_RELAXED, __HIP_MEMORY_SCOPE_AGENT);
                    }
                }
            }
        }

        // inter-step device barrier (skip after last step: kernel boundary covers it)
        if (j < CH_ - 1)
            grid_bar(bar + (size_t)j * BARSTR);
    }

    if (active) {
#pragma unroll
        for (int rep = 0; rep < 2; rep++) {
            int cell = tid + rep * 256;
            cst[(long)(cell >> 3) * H_ + nb * 8 + (cell & 7)] = creg[rep];
        }
    }
}

// zero c-states, carry-in h slots, and barrier counters
__global__ __launch_bounds__(256) void init_k(
    float* c0, float* c1, bf16* h0w, bf16* h1w, unsigned* bar, int nbar)
{
    int i = blockIdx.x * 256 + threadIdx.x;
    if (i < B_ * H_) {
        c0[i] = 0.f; c1[i] = 0.f;
        h0w[i] = f2bf(0.f);   // buf 0, slot 0
        h1w[i] = f2bf(0.f);   // slot 0
    }
    if (i < nbar) bar[i] = 0u;
}

// h_n: layer0 = h0w buf0 slot0 (final carry), layer1 = h1w slot0. c_n fp32.
__global__ __launch_bounds__(256) void finalize_k(
    const bf16* __restrict__ h0w, const bf16* __restrict__ h1w,
    const float* __restrict__ c0, const float* __restrict__ c1,
    float* __restrict__ out_hn, float* __restrict__ out_cn)
{
    int i = blockIdx.x * 256 + threadIdx.x;
    if (i < B_ * H_) {
        out_hn[i]            = bf2f(h0w[i]);
        out_hn[B_ * H_ + i]  = bf2f(h1w[i]);
        out_cn[i]            = c0[i];
        out_cn[B_ * H_ + i]  = c1[i];
    }
}

extern "C" void kernel_launch(void* const* d_in, const int* in_sizes, int n_in,
                              void* d_out, int out_size, void* d_ws, size_t ws_size,
                              hipStream_t stream)
{
    const float* x    = (const float*)d_in[0];
    const float* Wih0 = (const float*)d_in[1];
    const float* Whh0 = (const float*)d_in[2];
    const float* bih0 = (const float*)d_in[3];
    const float* bhh0 = (const float*)d_in[4];
    const float* Wih1 = (const float*)d_in[5];
    const float* Whh1 = (const float*)d_in[6];
    const float* bih1 = (const float*)d_in[7];
    const float* bhh1 = (const float*)d_in[8];
    const float* Wfc  = (const float*)d_in[9];
    const float* bfc  = (const float*)d_in[10];
    float* out = (float*)d_out;

    // workspace (~45 MB + 70 KB barriers)
    char* p = (char*)d_ws;
    float* c0  = (float*)p; p += (size_t)B_ * H_ * 4;                       // 256 KB
    float* c1  = (float*)p; p += (size_t)B_ * H_ * 4;                       // 256 KB
    bf16* h0w  = (bf16*)p;  p += (size_t)2 * (CH_ + 1) * B_ * H_ * 2;       // 8.25 MB
    bf16* h1w  = (bf16*)p;  p += (size_t)(CH_ + 1) * B_ * H_ * 2;           // 4.13 MB
    bf16* xg0  = (bf16*)p;  p += (size_t)CH_ * B_ * G4H * 2;                // 16 MB
    bf16* xg1  = (bf16*)p;  p += (size_t)CH_ * B_ * G4H * 2;                // 16 MB
    unsigned* bar = (unsigned*)p; p += (size_t)(NCH + 1) * CH_ * BARSTR * 4;// 70 KB

    const int nbar = (NCH + 1) * CH_ * BARSTR;
    init_k<<<(B_ * H_ + 255) / 256, 256, 0, stream>>>(c0, c1, h0w, h1w, bar, nbar);

    const dim3 gxg0((B_ * CH_) / 128, G4H / 128);  // 16 x 32
    const dim3 gfc((B_ * CH_) / 128, O_ / 128);    // 16 x 4

    // Diagonal pipeline over 17 groups: layer0 on chunk c, layer1 on chunk c-1.
    for (int c = 0; c <= NCH; c++) {
        const int do0 = (c < NCH);
        const int do1 = (c >= 1);

        if (do0) {
            // xg0(c): xg0[t][b] = x[b][c*CH+t] @ Wih0^T + bih0 + bhh0   (A fp32)
            gemm_bt<1, 0, 0, bf16><<<gxg0, 256, 0, stream>>>(
                x, Wih0, xg0, bih0, bhh0, B_ * CH_, G4H, I_, c * CH_);
        }
        if (do1) {
            // xg1(c-1): from h0 window buf (c-1)&1, slots 1..CH           (A bf16)
            const bf16* h0chunk = h0w + (size_t)((c - 1) & 1) * (CH_ + 1) * B_ * H_ + B_ * H_;
            gemm_bt<0, 0, 1, bf16><<<gxg0, 256, 0, stream>>>(
                h0chunk, Wih1, xg1, bih1, bhh1, B_ * CH_, G4H, H_, 0);
        }

        // one persistent cooperative launch = all CH_ steps of this group
        {
            const bf16*  a0  = xg0;  const bf16*  a1  = xg1;
            const float* w0  = Whh0; const float* w1  = Whh1;
            bf16* hp0 = h0w; bf16* hp1 = h1w;
            float* cp0 = c0; float* cp1 = c1;
            unsigned* bp = bar + (size_t)c * CH_ * BARSTR;
            int cv = c, d0 = do0, d1 = do1;
            void* args[] = { &a0, &a1, &w0, &w1, &hp0, &hp1,
                             &cp0, &cp1, &bp, &cv, &d0, &d1 };
            hipLaunchCooperativeKernel((const void*)chunk_k,
                                       dim3(NBLK), dim3(256), args, 0, stream);
        }

        if (do1) {
            // FC on layer-1 chunk c-1: out rows t0=(c-1)*CH              (A bf16, C fp32)
            gemm_bt<0, 2, 1, float><<<gfc, 256, 0, stream>>>(
                h1w + B_ * H_, Wfc, out, bfc, (const float*)nullptr,
                B_ * CH_, O_, H_, (c - 1) * CH_);
        }
    }

    finalize_k<<<(B_ * H_ + 255) / 256, 256, 0, stream>>>(
        h0w, h1w, c0, c1,
        out + (size_t)B_ * S_ * O_,
        out + (size_t)B_ * S_ * O_ + 2 * (size_t)B_ * H_);
}

// Round 4
// 9149.747 us; speedup vs baseline: 3.4126x; 1.1411x over previous
//
#include <hip/hip_runtime.h>
#include <hip/hip_bf16.h>

#define B_   64
#define S_   512
#define I_   512
#define H_   1024
#define G4H  4096
#define O_   512
#define CH_  32    // timesteps per chunk
#define NCH  (S_ / CH_)   // 16 chunks per layer

#define NBLK    256       // chunk_k grid: 128 blocks/layer (32 gate-cols each)
#define STRIPES 16        // barrier stripes (separate cachelines)
#define BARSTR  32        // uints per stripe (128B)

typedef short s16x8 __attribute__((ext_vector_type(8)));
typedef short s16x4 __attribute__((ext_vector_type(4)));
typedef float f32x4 __attribute__((ext_vector_type(4)));
typedef unsigned long long u64;
using bf16 = __hip_bfloat16;

__device__ __forceinline__ float bf2f(bf16 v) { return __bfloat162float(v); }
__device__ __forceinline__ bf16  f2bf(float f) { return __float2bfloat16(f); }
__device__ __forceinline__ short f2bfb(float f) { bf16 h = __float2bfloat16(f); return *(short*)&h; }

__device__ __forceinline__ void storeC(float* p, float v) { *p = v; }
__device__ __forceinline__ void storeC(bf16* p, float v)  { *p = f2bf(v); }

// ---------------------------------------------------------------------------
// C = A @ Bw^T (+bias1+bias2). Bw fp32 global (bf16-converted while staging).
// Tile 128x128, BK=32, 256 threads (4 waves, 64x64 quadrant each).
// ---------------------------------------------------------------------------
template <int AMAP, int CMAP, int ABF, typename CT>
__global__ __launch_bounds__(256) void gemm_bt(
    const void* __restrict__ Av, const float* __restrict__ Bw,
    CT* __restrict__ C,
    const float* __restrict__ bias1, const float* __restrict__ bias2,
    int M, int N, int K, int t0)
{
    __shared__ bf16 As[128 * 40];
    __shared__ bf16 Bs[128 * 40];

    const int tid  = threadIdx.x;
    const int wave = tid >> 6;
    const int lane = tid & 63;
    const int quad = lane >> 4;
    const int l16  = lane & 15;

    const int m_base = blockIdx.x * 128;
    const int n_base = blockIdx.y * 128;
    const int wm = (wave >> 1) * 64;
    const int wn = (wave & 1) * 64;

    f32x4 acc[4][4] = {};

    for (int k0 = 0; k0 < K; k0 += 32) {
        __syncthreads();
#pragma unroll
        for (int i = 0; i < 2; i++) {
            int l   = tid + i * 256;     // 0..511
            int row = l >> 2;            // 0..127
            int ko  = (l & 3) * 8;       // 0,8,16,24
            int m   = m_base + row;
            long ar = m;
            if (AMAP == 1) ar = (long)(m & 63) * S_ + t0 + (m >> 6);

            if (ABF) {
                const bf16* ap = (const bf16*)Av + ar * (long)K + k0 + ko;
                *(s16x8*)(&As[row * 40 + ko]) = *(const s16x8*)ap;
            } else {
                const float* ap = (const float*)Av + ar * (long)K + k0 + ko;
                f32x4 a0 = *(const f32x4*)ap;
                f32x4 a1 = *(const f32x4*)(ap + 4);
                s16x8 av;
#pragma unroll
                for (int j = 0; j < 4; j++) { av[j] = f2bfb(a0[j]); av[4 + j] = f2bfb(a1[j]); }
                *(s16x8*)(&As[row * 40 + ko]) = av;
            }

            const float* bp = &Bw[(long)(n_base + row) * K + k0 + ko];
            f32x4 b0 = *(const f32x4*)bp;
            f32x4 b1 = *(const f32x4*)(bp + 4);
            s16x8 bv;
#pragma unroll
            for (int j = 0; j < 4; j++) { bv[j] = f2bfb(b0[j]); bv[4 + j] = f2bfb(b1[j]); }
            *(s16x8*)(&Bs[row * 40 + ko]) = bv;
        }
        __syncthreads();

        s16x8 af[4], bfr[4];
#pragma unroll
        for (int i = 0; i < 4; i++)
            af[i] = *(const s16x8*)(&As[(wm + i * 16 + l16) * 40 + quad * 8]);
#pragma unroll
        for (int j = 0; j < 4; j++)
            bfr[j] = *(const s16x8*)(&Bs[(wn + j * 16 + l16) * 40 + quad * 8]);
#pragma unroll
        for (int i = 0; i < 4; i++)
#pragma unroll
            for (int j = 0; j < 4; j++)
                acc[i][j] = __builtin_amdgcn_mfma_f32_16x16x32_bf16(af[i], bfr[j], acc[i][j], 0, 0, 0);
    }

    // C/D layout: col = lane&15, row = (lane>>4)*4 + reg
#pragma unroll
    for (int i = 0; i < 4; i++) {
#pragma unroll
        for (int j = 0; j < 4; j++) {
#pragma unroll
            for (int r = 0; r < 4; r++) {
                int m = m_base + wm + i * 16 + quad * 4 + r;
                int n = n_base + wn + j * 16 + l16;
                float v = acc[i][j][r];
                if (bias1) v += bias1[n];
                if (bias2) v += bias2[n];
                long cr = m;
                if (CMAP == 2) cr = (long)(m & 63) * S_ + t0 + (m >> 6);
                storeC(&C[cr * (long)N + n], v);
            }
        }
    }
}

// ---------------------------------------------------------------------------
// Striped fence-free device barrier, counters REUSED across the 17 sequential
// launches (monotonic; group c waits for (c+1)*16 per stripe). 16 stripes, one
// cacheline each: block bid&15 RMWs its stripe (16 arrivals/line, parallel
// across lines); lanes 0..15 of wave 0 poll the 16 stripes concurrently.
// All cross-block data moves via agent-scope relaxed atomics (sc1, coherent
// point) -> no cache-maintenance fences. __syncthreads before the arrive
// drains the wave's sc1 stores (vmcnt ack = agent-visible per gfx94x model).
// ---------------------------------------------------------------------------
__device__ __forceinline__ void grid_bar(unsigned* ctr, unsigned target)
{
    __syncthreads();
    const int t = threadIdx.x;
    if (t == 0)
        __hip_atomic_fetch_add(ctr + (blockIdx.x & (STRIPES - 1)) * BARSTR, 1u,
                               __ATOMIC_RELAXED, __HIP_MEMORY_SCOPE_AGENT);
    if (t < STRIPES) {
        while (__hip_atomic_load(ctr + t * BARSTR, __ATOMIC_RELAXED,
                                 __HIP_MEMORY_SCOPE_AGENT) < target)
            __builtin_amdgcn_s_sleep(1);
    }
    __syncthreads();
}

// ---------------------------------------------------------------------------
// Persistent per-chunk recurrence (PROVEN round-2 geometry). 256 blocks:
// [0,128) layer 0 (iff do0), [128,256) layer 1 (iff do1). Each block owns
// 8 hidden units = 32 gate-cols. Whh slice (32 x 1024) staged fp32->bf16 in
// LDS once per chunk; c-state in registers. h window via agent-scope relaxed
// atomics; ALL 64 8B h-loads issued up-front (single L3 latency exposure).
// ---------------------------------------------------------------------------
__global__ __launch_bounds__(256, 1) void chunk_k(
    const bf16* __restrict__ xg0,  // [CH][B][4H] layer-0 input contrib, chunk cpar
    const bf16* __restrict__ xg1,  // [CH][B][4H] layer-1 input contrib, chunk cpar-1
    const float* __restrict__ Whh0,
    const float* __restrict__ Whh1,
    bf16* __restrict__ h0w,        // [2][CH+1][B][H] double-buffered window
    bf16* __restrict__ h1w,        // [CH+1][B][H]
    float* __restrict__ c0,
    float* __restrict__ c1,
    unsigned* __restrict__ bar,    // [CH][STRIPES][BARSTR], zeroed once, reused
    int cpar, int do0, int do1)
{
    const int layer  = blockIdx.x >> 7;
    const int nb     = blockIdx.x & 127;
    const int active = layer ? do1 : do0;   // block-uniform

    const bf16*  xg  = layer ? xg1  : xg0;
    const float* Whh = layer ? Whh1 : Whh0;
    float*       cst = layer ? c1   : c0;

    bf16 *rbuf, *cbuf;
    if (layer == 0) {
        rbuf = h0w + (size_t)(cpar & 1) * (CH_ + 1) * B_ * H_;
        cbuf = h0w + (size_t)((cpar + 1) & 1) * (CH_ + 1) * B_ * H_;
    } else {
        rbuf = h1w; cbuf = h1w;
    }

    const int tid  = threadIdx.x;
    const int lane = tid & 63;
    const int wave = tid >> 6;
    const int quad = lane >> 4;
    const int l16  = lane & 15;

    const unsigned bar_target = (unsigned)(cpar + 1) * (NBLK / STRIPES);

    __shared__ bf16  wsh[32][1032];  // 66 KB; +8 pad: 2-way aliasing only (free)
    __shared__ float gs[64][36];     // 9.2 KB

    // stage Whh slice (32 gate-rows x 1024) fp32 -> bf16 LDS, ONCE per chunk.
    // row r <-> Whh row (r>>3)*H + nb*8 + (r&7)   (gate g = r>>3, unit uu = r&7)
    if (active) {
        int r  = tid >> 3;                 // 0..31
        int cc = (tid & 7) * 128;          // 128 elems per thread
        const float* src = Whh + ((long)(r >> 3) * H_ + nb * 8 + (r & 7)) * H_ + cc;
#pragma unroll
        for (int q = 0; q < 128; q += 4) {
            f32x4 v = *(const f32x4*)(src + q);
            s16x4 o;
#pragma unroll
            for (int w = 0; w < 4; w++) o[w] = f2bfb(v[w]);
            *(s16x4*)(&wsh[r][cc + q]) = o;
        }
    }
    __syncthreads();

    // c-state in registers: cell = tid + rep*256, bb = cell>>3, uu = cell&7
    float creg[2];
#pragma unroll
    for (int rep = 0; rep < 2; rep++) {
        int cell = tid + rep * 256;
        creg[rep] = active ? cst[(long)(cell >> 3) * H_ + nb * 8 + (cell & 7)] : 0.f;
    }

    for (int j = 0; j < CH_; j++) {
        if (active) {
            // xg gather for this step's epilogue (issued early, hides under MFMA)
            const bf16* xgt = xg + (long)j * (B_ * G4H);
            float xv0[4], xv1[4];
#pragma unroll
            for (int r = 0; r < 4; r++) {
                int m   = wave * 16 + quad * 4 + r;
                int c0i = l16;
                int c1i = 16 + l16;
                xv0[r] = bf2f(xgt[(long)m * G4H + (long)(c0i >> 3) * H_ + nb * 8 + (c0i & 7)]);
                xv1[r] = bf2f(xgt[(long)m * G4H + (long)(c1i >> 3) * H_ + nb * 8 + (c1i & 7)]);
            }

            // h(t) row (wave*16+l16), full K=1024: all 64 8B agent-relaxed loads
            // issued BEFORE any MFMA (one L3 latency exposure).
            const u64* ap = (const u64*)(rbuf + (long)j * (B_ * H_)
                           + (long)(wave * 16 + l16) * H_) + quad * 2;
            u64 la[32], lb[32];
#pragma unroll
            for (int t = 0; t < 32; t++) {
                u64* p = (u64*)(ap + (size_t)t * 8);
                la[t] = __hip_atomic_load(p,     __ATOMIC_RELAXED, __HIP_MEMORY_SCOPE_AGENT);
                lb[t] = __hip_atomic_load(p + 1, __ATOMIC_RELAXED, __HIP_MEMORY_SCOPE_AGENT);
            }

            f32x4 acc0 = {}, acc1 = {};
#pragma unroll
            for (int t = 0; t < 32; t++) {
                union { u64 q[2]; s16x8 v; } ua;
                ua.q[0] = la[t]; ua.q[1] = lb[t];
                int k = t * 32;
                s16x8 b0 = *(const s16x8*)(&wsh[l16][k + quad * 8]);
                s16x8 b1 = *(const s16x8*)(&wsh[16 + l16][k + quad * 8]);
                acc0 = __builtin_amdgcn_mfma_f32_16x16x32_bf16(ua.v, b0, acc0, 0, 0, 0);
                acc1 = __builtin_amdgcn_mfma_f32_16x16x32_bf16(ua.v, b1, acc1, 0, 0, 0);
            }

            // C layout: col = l16 (+16 for frag1), row = quad*4 + reg
#pragma unroll
            for (int r = 0; r < 4; r++) {
                int m = wave * 16 + quad * 4 + r;
                gs[m][l16]      = acc0[r] + xv0[r];
                gs[m][16 + l16] = acc1[r] + xv1[r];
            }
        }
        __syncthreads();

        if (active) {
            unsigned short hb[2];
#pragma unroll
            for (int rep = 0; rep < 2; rep++) {
                int cell = tid + rep * 256;
                int bb = cell >> 3, uu = cell & 7;
                float gi = gs[bb][uu];
                float gf = gs[bb][8 + uu];
                float gg = gs[bb][16 + uu];
                float go = gs[bb][24 + uu];

                float ig = 1.f / (1.f + __expf(-gi));
                float fg = 1.f / (1.f + __expf(-gf));
                float og = 1.f / (1.f + __expf(-go));
                float e2 = __expf(-2.f * fabsf(gg));
                float tg = (1.f - e2) / (1.f + e2);
                tg = (gg < 0.f) ? -tg : tg;

                creg[rep] = fg * creg[rep] + ig * tg;
                float e2c = __expf(-2.f * fabsf(creg[rep]));
                float tc = (1.f - e2c) / (1.f + e2c);
                tc = (creg[rep] < 0.f) ? -tc : tc;

                bf16 hv = f2bf(og * tc);
                hb[rep] = *(unsigned short*)&hv;
            }
            // pair adjacent units via shfl -> 4B agent-relaxed stores
#pragma unroll
            for (int rep = 0; rep < 2; rep++) {
                int cell = tid + rep * 256;
                int bb = cell >> 3, uu = cell & 7;
                unsigned my    = hb[rep];
                unsigned other = (unsigned)__shfl((int)my, lane ^ 1, 64);
                if (!(uu & 1)) {
                    unsigned v32 = my | (other << 16);
                    unsigned* dst = (unsigned*)(rbuf + (long)(j + 1) * (B_ * H_)
                                    + (long)bb * H_ + nb * 8 + uu);
                    __hip_atomic_store(dst, v32, __ATOMIC_RELAXED, __HIP_MEMORY_SCOPE_AGENT);
                    if (j == CH_ - 1) {
                        unsigned* cd = (unsigned*)(cbuf + (long)bb * H_ + nb * 8 + uu);
                        __hip_atomic_store(cd, v32, __ATOMIC_RELAXED, __HIP_MEMORY_SCOPE_AGENT);
                    }
                }
            }
        }

        // inter-step device barrier (skip after last step: kernel boundary covers it)
        if (j < CH_ - 1)
            grid_bar(bar + (size_t)j * STRIPES * BARSTR, bar_target);
    }

    if (active) {
#pragma unroll
        for (int rep = 0; rep < 2; rep++) {
            int cell = tid + rep * 256;
            cst[(long)(cell >> 3) * H_ + nb * 8 + (cell & 7)] = creg[rep];
        }
    }
}

// zero c-states, carry-in h slots, and barrier counters
__global__ __launch_bounds__(256) void init_k(
    float* c0, float* c1, bf16* h0w, bf16* h1w, unsigned* bar, int nbar)
{
    int i = blockIdx.x * 256 + threadIdx.x;
    if (i < B_ * H_) {
        c0[i] = 0.f; c1[i] = 0.f;
        h0w[i] = f2bf(0.f);   // buf 0, slot 0
        h1w[i] = f2bf(0.f);   // slot 0
    }
    if (i < nbar) bar[i] = 0u;
}

// h_n: layer0 = h0w buf0 slot0 (final carry), layer1 = h1w slot0. c_n fp32.
__global__ __launch_bounds__(256) void finalize_k(
    const bf16* __restrict__ h0w, const bf16* __restrict__ h1w,
    const float* __restrict__ c0, const float* __restrict__ c1,
    float* __restrict__ out_hn, float* __restrict__ out_cn)
{
    int i = blockIdx.x * 256 + threadIdx.x;
    if (i < B_ * H_) {
        out_hn[i]            = bf2f(h0w[i]);
        out_hn[B_ * H_ + i]  = bf2f(h1w[i]);
        out_cn[i]            = c0[i];
        out_cn[B_ * H_ + i]  = c1[i];
    }
}

extern "C" void kernel_launch(void* const* d_in, const int* in_sizes, int n_in,
                              void* d_out, int out_size, void* d_ws, size_t ws_size,
                              hipStream_t stream)
{
    const float* x    = (const float*)d_in[0];
    const float* Wih0 = (const float*)d_in[1];
    const float* Whh0 = (const float*)d_in[2];
    const float* bih0 = (const float*)d_in[3];
    const float* bhh0 = (const float*)d_in[4];
    const float* Wih1 = (const float*)d_in[5];
    const float* Whh1 = (const float*)d_in[6];
    const float* bih1 = (const float*)d_in[7];
    const float* bhh1 = (const float*)d_in[8];
    const float* Wfc  = (const float*)d_in[9];
    const float* bfc  = (const float*)d_in[10];
    float* out = (float*)d_out;

    // workspace (~45.2 MB total — within the proven round-0/1/2 envelope)
    char* p = (char*)d_ws;
    float* c0  = (float*)p; p += (size_t)B_ * H_ * 4;                       // 256 KB
    float* c1  = (float*)p; p += (size_t)B_ * H_ * 4;                       // 256 KB
    bf16* h0w  = (bf16*)p;  p += (size_t)2 * (CH_ + 1) * B_ * H_ * 2;       // 8.25 MB
    bf16* h1w  = (bf16*)p;  p += (size_t)(CH_ + 1) * B_ * H_ * 2;           // 4.13 MB
    bf16* xg0  = (bf16*)p;  p += (size_t)CH_ * B_ * G4H * 2;                // 16 MB
    bf16* xg1  = (bf16*)p;  p += (size_t)CH_ * B_ * G4H * 2;                // 16 MB
    unsigned* bar = (unsigned*)p;
    const int nbar = CH_ * STRIPES * BARSTR;                                // 64 KB, reused
    p += (size_t)nbar * 4;

    init_k<<<(B_ * H_ + 255) / 256, 256, 0, stream>>>(c0, c1, h0w, h1w, bar, nbar);

    const dim3 gxg0((B_ * CH_) / 128, G4H / 128);  // 16 x 32
    const dim3 gfc((B_ * CH_) / 128, O_ / 128);    // 16 x 4

    // Diagonal pipeline over 17 groups: layer0 on chunk c, layer1 on chunk c-1.
    for (int c = 0; c <= NCH; c++) {
        const int do0 = (c < NCH);
        const int do1 = (c >= 1);

        if (do0) {
            // xg0(c): xg0[t][b] = x[b][c*CH+t] @ Wih0^T + bih0 + bhh0   (A fp32)
            gemm_bt<1, 0, 0, bf16><<<gxg0, 256, 0, stream>>>(
                x, Wih0, xg0, bih0, bhh0, B_ * CH_, G4H, I_, c * CH_);
        }
        if (do1) {
            // xg1(c-1): from h0 window buf (c-1)&1, slots 1..CH           (A bf16)
            const bf16* h0chunk = h0w + (size_t)((c - 1) & 1) * (CH_ + 1) * B_ * H_ + B_ * H_;
            gemm_bt<0, 0, 1, bf16><<<gxg0, 256, 0, stream>>>(
                h0chunk, Wih1, xg1, bih1, bhh1, B_ * CH_, G4H, H_, 0);
        }

        // one persistent cooperative launch = all CH_ steps of this group
        {
            const bf16*  a0  = xg0;  const bf16*  a1  = xg1;
            const float* w0  = Whh0; const float* w1  = Whh1;
            bf16* hp0 = h0w; bf16* hp1 = h1w;
            float* cp0 = c0; float* cp1 = c1;
            unsigned* bp = bar;
            int cv = c, d0 = do0, d1 = do1;
            void* args[] = { &a0, &a1, &w0, &w1, &hp0, &hp1,
                             &cp0, &cp1, &bp, &cv, &d0, &d1 };
            hipLaunchCooperativeKernel((const void*)chunk_k,
                                       dim3(NBLK), dim3(256), args, 0, stream);
        }

        if (do1) {
            // FC on layer-1 chunk c-1: out rows t0=(c-1)*CH              (A bf16, C fp32)
            gemm_bt<0, 2, 1, float><<<gfc, 256, 0, stream>>>(
                h1w + B_ * H_, Wfc, out, bfc, (const float*)nullptr,
                B_ * CH_, O_, H_, (c - 1) * CH_);
        }
    }

    finalize_k<<<(B_ * H_ + 255) / 256, 256, 0, stream>>>(
        h0w, h1w, c0, c1,
        out + (size_t)B_ * S_ * O_,
        out + (size_t)B_ * S_ * O_ + 2 * (size_t)B_ * H_);
}

// Round 5
// 8140.524 us; speedup vs baseline: 3.8357x; 1.1240x over previous
//
#include <hip/hip_runtime.h>
#include <hip/hip_bf16.h>

#define B_   64
#define S_   512
#define I_   512
#define H_   1024
#define G4H  4096
#define O_   512
#define CH_  32    // timesteps per chunk
#define NCH  (S_ / CH_)   // 16 chunks per layer

#define NBLK   256        // chunk_k grid: 128 blocks/layer (8 hidden units each)
#define THR_   512        // threads per chunk_k block (8 waves)
#define LSTR   8          // barrier stripes per layer
#define BARSTR 32         // uints per stripe (128B, own cacheline)

typedef short s16x8 __attribute__((ext_vector_type(8)));
typedef short s16x4 __attribute__((ext_vector_type(4)));
typedef float f32x4 __attribute__((ext_vector_type(4)));
typedef unsigned long long u64;
using bf16 = __hip_bfloat16;

__device__ __forceinline__ float bf2f(bf16 v) { return __bfloat162float(v); }
__device__ __forceinline__ bf16  f2bf(float f) { return __float2bfloat16(f); }
__device__ __forceinline__ short f2bfb(float f) { bf16 h = __float2bfloat16(f); return *(short*)&h; }

__device__ __forceinline__ void storeC(float* p, float v) { *p = v; }
__device__ __forceinline__ void storeC(bf16* p, float v)  { *p = f2bf(v); }

// ---------------------------------------------------------------------------
// C = A @ Bw^T (+bias1+bias2). Bw fp32 global (bf16-converted while staging).
// Tile 128x128, BK=32, 256 threads (4 waves, 64x64 quadrant each).
// ---------------------------------------------------------------------------
template <int AMAP, int CMAP, int ABF, typename CT>
__global__ __launch_bounds__(256) void gemm_bt(
    const void* __restrict__ Av, const float* __restrict__ Bw,
    CT* __restrict__ C,
    const float* __restrict__ bias1, const float* __restrict__ bias2,
    int M, int N, int K, int t0)
{
    __shared__ bf16 As[128 * 40];
    __shared__ bf16 Bs[128 * 40];

    const int tid  = threadIdx.x;
    const int wave = tid >> 6;
    const int lane = tid & 63;
    const int quad = lane >> 4;
    const int l16  = lane & 15;

    const int m_base = blockIdx.x * 128;
    const int n_base = blockIdx.y * 128;
    const int wm = (wave >> 1) * 64;
    const int wn = (wave & 1) * 64;

    f32x4 acc[4][4] = {};

    for (int k0 = 0; k0 < K; k0 += 32) {
        __syncthreads();
#pragma unroll
        for (int i = 0; i < 2; i++) {
            int l   = tid + i * 256;     // 0..511
            int row = l >> 2;            // 0..127
            int ko  = (l & 3) * 8;       // 0,8,16,24
            int m   = m_base + row;
            long ar = m;
            if (AMAP == 1) ar = (long)(m & 63) * S_ + t0 + (m >> 6);

            if (ABF) {
                const bf16* ap = (const bf16*)Av + ar * (long)K + k0 + ko;
                *(s16x8*)(&As[row * 40 + ko]) = *(const s16x8*)ap;
            } else {
                const float* ap = (const float*)Av + ar * (long)K + k0 + ko;
                f32x4 a0 = *(const f32x4*)ap;
                f32x4 a1 = *(const f32x4*)(ap + 4);
                s16x8 av;
#pragma unroll
                for (int j = 0; j < 4; j++) { av[j] = f2bfb(a0[j]); av[4 + j] = f2bfb(a1[j]); }
                *(s16x8*)(&As[row * 40 + ko]) = av;
            }

            const float* bp = &Bw[(long)(n_base + row) * K + k0 + ko];
            f32x4 b0 = *(const f32x4*)bp;
            f32x4 b1 = *(const f32x4*)(bp + 4);
            s16x8 bv;
#pragma unroll
            for (int j = 0; j < 4; j++) { bv[j] = f2bfb(b0[j]); bv[4 + j] = f2bfb(b1[j]); }
            *(s16x8*)(&Bs[row * 40 + ko]) = bv;
        }
        __syncthreads();

        s16x8 af[4], bfr[4];
#pragma unroll
        for (int i = 0; i < 4; i++)
            af[i] = *(const s16x8*)(&As[(wm + i * 16 + l16) * 40 + quad * 8]);
#pragma unroll
        for (int j = 0; j < 4; j++)
            bfr[j] = *(const s16x8*)(&Bs[(wn + j * 16 + l16) * 40 + quad * 8]);
#pragma unroll
        for (int i = 0; i < 4; i++)
#pragma unroll
            for (int j = 0; j < 4; j++)
                acc[i][j] = __builtin_amdgcn_mfma_f32_16x16x32_bf16(af[i], bfr[j], acc[i][j], 0, 0, 0);
    }

    // C/D layout: col = lane&15, row = (lane>>4)*4 + reg
#pragma unroll
    for (int i = 0; i < 4; i++) {
#pragma unroll
        for (int j = 0; j < 4; j++) {
#pragma unroll
            for (int r = 0; r < 4; r++) {
                int m = m_base + wm + i * 16 + quad * 4 + r;
                int n = n_base + wn + j * 16 + l16;
                float v = acc[i][j][r];
                if (bias1) v += bias1[n];
                if (bias2) v += bias2[n];
                long cr = m;
                if (CMAP == 2) cr = (long)(m & 63) * S_ + t0 + (m >> 6);
                storeC(&C[cr * (long)N + n], v);
            }
        }
    }
}

// ---------------------------------------------------------------------------
// Per-layer striped fence-free barrier. Domain = the 128 blocks of one layer
// (the recurrence has no cross-layer data dependency within a launch).
// 8 stripes/layer, one cacheline each; block (bid&127)&7 RMWs its stripe
// (16 arrivals/line); lanes 0..7 poll the 8 stripes concurrently. Counters
// are monotonic and REUSED across the 17 sequential launches via per-layer
// participation targets. All cross-block data moves via agent-scope relaxed
// atomics (sc1, coherent point) -> no cache-maintenance fences needed;
// __syncthreads before the arrive drains the wave's sc1 stores (vmcnt ack).
// ---------------------------------------------------------------------------
__device__ __forceinline__ void grid_bar(unsigned* ctr, unsigned target)
{
    __syncthreads();
    const int t = threadIdx.x;
    if (t == 0)
        __hip_atomic_fetch_add(ctr + ((blockIdx.x & 127) & (LSTR - 1)) * BARSTR, 1u,
                               __ATOMIC_RELAXED, __HIP_MEMORY_SCOPE_AGENT);
    if (t < LSTR) {
        while (__hip_atomic_load(ctr + t * BARSTR, __ATOMIC_RELAXED,
                                 __HIP_MEMORY_SCOPE_AGENT) < target)
            __builtin_amdgcn_s_sleep(1);
    }
    __syncthreads();
}

// ---------------------------------------------------------------------------
// Persistent per-chunk recurrence (round-4 data layout, 512 threads).
// 256 blocks: [0,128) layer 0 (iff do0), [128,256) layer 1 (iff do1);
// inactive blocks return immediately (per-layer barrier domains).
// Each block owns 8 hidden units = 32 gate-cols. Whh slice (32 x 1024)
// staged fp32->bf16 in LDS once per chunk. 8 waves: wave = (kw, mw);
// wave (kw,mw) computes rows mw*16+l16 over K-half kw (32 loads + 32 MFMA),
// partials meet in gs[2] (fp32 add in epilogue). xg for step j+1 is
// prefetched into registers before the barrier wait. c-state in registers.
// ---------------------------------------------------------------------------
__global__ __launch_bounds__(THR_, 1) void chunk_k(
    const bf16* __restrict__ xg0,  // [CH][B][4H] layer-0 input contrib, chunk cpar
    const bf16* __restrict__ xg1,  // [CH][B][4H] layer-1 input contrib, chunk cpar-1
    const float* __restrict__ Whh0,
    const float* __restrict__ Whh1,
    bf16* __restrict__ h0w,        // [2][CH+1][B][H] double-buffered window
    bf16* __restrict__ h1w,        // [CH+1][B][H]
    float* __restrict__ c0,
    float* __restrict__ c1,
    unsigned* __restrict__ bar,    // [2][CH][LSTR][BARSTR], zeroed once, reused
    int cpar, int do0, int do1)
{
    const int layer  = blockIdx.x >> 7;
    const int nb     = blockIdx.x & 127;
    const int active = layer ? do1 : do0;   // block-uniform
    if (!active) return;

    const bf16*  xg  = layer ? xg1  : xg0;
    const float* Whh = layer ? Whh1 : Whh0;
    float*       cst = layer ? c1   : c0;

    bf16 *rbuf, *cbuf;
    if (layer == 0) {
        rbuf = h0w + (size_t)(cpar & 1) * (CH_ + 1) * B_ * H_;
        cbuf = h0w + (size_t)((cpar + 1) & 1) * (CH_ + 1) * B_ * H_;
    } else {
        rbuf = h1w; cbuf = h1w;
    }

    const int tid  = threadIdx.x;
    const int lane = tid & 63;
    const int wave = tid >> 6;     // 0..7
    const int quad = lane >> 4;
    const int l16  = lane & 15;
    const int kw   = wave >> 2;    // K-half (0: k<512, 1: k>=512)
    const int mw   = wave & 3;     // row-group (rows mw*16 + l16)

    // per-layer barrier region + monotonic reuse target
    unsigned* barL = bar + (size_t)layer * CH_ * LSTR * BARSTR;
    const unsigned bar_tgt =
        (layer ? (unsigned)cpar : (unsigned)(cpar + 1)) * (128 / LSTR);

    __shared__ bf16  wsh[32][1032];   // 66 KB; +8 pad: 2-way aliasing only
    __shared__ float gs[2][64][36];   // 18.4 KB; [K-half][batch][gate-col]

    // stage Whh slice (32 gate-rows x 1024) fp32 -> bf16 LDS, ONCE per chunk.
    // row r <-> Whh row (r>>3)*H + nb*8 + (r&7)   (gate g = r>>3, unit uu = r&7)
    {
        int r  = tid >> 4;                 // 0..31
        int cc = (tid & 15) * 64;          // 64 elems per thread
        const float* src = Whh + ((long)(r >> 3) * H_ + nb * 8 + (r & 7)) * H_ + cc;
#pragma unroll
        for (int q = 0; q < 64; q += 4) {
            f32x4 v = *(const f32x4*)(src + q);
            s16x4 o;
#pragma unroll
            for (int w = 0; w < 4; w++) o[w] = f2bfb(v[w]);
            *(s16x4*)(&wsh[r][cc + q]) = o;
        }
    }
    __syncthreads();

    // epilogue cell ownership: 512 threads = 64 batches x 8 units
    const int bb   = tid >> 3;
    const int uu   = tid & 7;
    const int unit = nb * 8 + uu;
    float creg = cst[(long)bb * H_ + unit];

    // prologue: xg prefetch for j=0 (4 gate values for this thread's cell)
    float xn[4];
#pragma unroll
    for (int g = 0; g < 4; g++)
        xn[g] = bf2f(xg[(long)bb * G4H + (long)g * H_ + unit]);

    for (int j = 0; j < CH_; j++) {
        // ---- MFMA phase: rows mw*16+l16, K-half kw ----
        const u64* ap = (const u64*)(rbuf + (long)j * (B_ * H_)
                       + (long)(mw * 16 + l16) * H_ + kw * 512) + quad * 2;
        u64 la[16], lb[16];
#pragma unroll
        for (int t = 0; t < 16; t++) {
            u64* p = (u64*)(ap + (size_t)t * 8);
            la[t] = __hip_atomic_load(p,     __ATOMIC_RELAXED, __HIP_MEMORY_SCOPE_AGENT);
            lb[t] = __hip_atomic_load(p + 1, __ATOMIC_RELAXED, __HIP_MEMORY_SCOPE_AGENT);
        }

        f32x4 acc0 = {}, acc1 = {};
#pragma unroll
        for (int t = 0; t < 16; t++) {
            union { u64 q[2]; s16x8 v; } ua;
            ua.q[0] = la[t]; ua.q[1] = lb[t];
            int k = kw * 512 + t * 32;
            s16x8 b0 = *(const s16x8*)(&wsh[l16][k + quad * 8]);
            s16x8 b1 = *(const s16x8*)(&wsh[16 + l16][k + quad * 8]);
            acc0 = __builtin_amdgcn_mfma_f32_16x16x32_bf16(ua.v, b0, acc0, 0, 0, 0);
            acc1 = __builtin_amdgcn_mfma_f32_16x16x32_bf16(ua.v, b1, acc1, 0, 0, 0);
        }

        // C layout: col = l16 (+16 for frag1), row = quad*4 + reg
#pragma unroll
        for (int r = 0; r < 4; r++) {
            int m = mw * 16 + quad * 4 + r;
            gs[kw][m][l16]      = acc0[r];
            gs[kw][m][16 + l16] = acc1[r];
        }
        __syncthreads();

        // ---- epilogue: combine K-half partials + prefetched xg ----
        {
            float gi = gs[0][bb][uu]      + gs[1][bb][uu]      + xn[0];
            float gf = gs[0][bb][8 + uu]  + gs[1][bb][8 + uu]  + xn[1];
            float gg = gs[0][bb][16 + uu] + gs[1][bb][16 + uu] + xn[2];
            float go = gs[0][bb][24 + uu] + gs[1][bb][24 + uu] + xn[3];

            float ig = 1.f / (1.f + __expf(-gi));
            float fg = 1.f / (1.f + __expf(-gf));
            float og = 1.f / (1.f + __expf(-go));
            float e2 = __expf(-2.f * fabsf(gg));
            float tg = (1.f - e2) / (1.f + e2);
            tg = (gg < 0.f) ? -tg : tg;

            creg = fg * creg + ig * tg;
            float e2c = __expf(-2.f * fabsf(creg));
            float tc = (1.f - e2c) / (1.f + e2c);
            tc = (creg < 0.f) ? -tc : tc;

            bf16 hv = f2bf(og * tc);
            unsigned my    = *(unsigned short*)&hv;
            unsigned other = (unsigned)__shfl((int)my, lane ^ 1, 64);
            if (!(uu & 1)) {
                unsigned v32 = my | (other << 16);
                unsigned* dst = (unsigned*)(rbuf + (long)(j + 1) * (B_ * H_)
                                + (long)bb * H_ + unit);
                __hip_atomic_store(dst, v32, __ATOMIC_RELAXED, __HIP_MEMORY_SCOPE_AGENT);
                if (j == CH_ - 1) {
                    unsigned* cd = (unsigned*)(cbuf + (long)bb * H_ + unit);
                    __hip_atomic_store(cd, v32, __ATOMIC_RELAXED, __HIP_MEMORY_SCOPE_AGENT);
                }
            }
        }

        // prefetch next step's xg (launch-constant; hides under barrier wait)
        if (j + 1 < CH_) {
            const bf16* xq = xg + (long)(j + 1) * (B_ * G4H);
#pragma unroll
            for (int g = 0; g < 4; g++)
                xn[g] = bf2f(xq[(long)bb * G4H + (long)g * H_ + unit]);
        }

        // inter-step per-layer barrier (skip after last step)
        if (j < CH_ - 1)
            grid_bar(barL + (size_t)j * LSTR * BARSTR, bar_tgt);
    }

    cst[(long)bb * H_ + unit] = creg;
}

// zero c-states, carry-in h slots, and barrier counters
__global__ __launch_bounds__(256) void init_k(
    float* c0, float* c1, bf16* h0w, bf16* h1w, unsigned* bar, int nbar)
{
    int i = blockIdx.x * 256 + threadIdx.x;
    if (i < B_ * H_) {
        c0[i] = 0.f; c1[i] = 0.f;
        h0w[i] = f2bf(0.f);   // buf 0, slot 0
        h1w[i] = f2bf(0.f);   // slot 0
    }
    if (i < nbar) bar[i] = 0u;
}

// h_n: layer0 = h0w buf0 slot0 (final carry), layer1 = h1w slot0. c_n fp32.
__global__ __launch_bounds__(256) void finalize_k(
    const bf16* __restrict__ h0w, const bf16* __restrict__ h1w,
    const float* __restrict__ c0, const float* __restrict__ c1,
    float* __restrict__ out_hn, float* __restrict__ out_cn)
{
    int i = blockIdx.x * 256 + threadIdx.x;
    if (i < B_ * H_) {
        out_hn[i]            = bf2f(h0w[i]);
        out_hn[B_ * H_ + i]  = bf2f(h1w[i]);
        out_cn[i]            = c0[i];
        out_cn[B_ * H_ + i]  = c1[i];
    }
}

extern "C" void kernel_launch(void* const* d_in, const int* in_sizes, int n_in,
                              void* d_out, int out_size, void* d_ws, size_t ws_size,
                              hipStream_t stream)
{
    const float* x    = (const float*)d_in[0];
    const float* Wih0 = (const float*)d_in[1];
    const float* Whh0 = (const float*)d_in[2];
    const float* bih0 = (const float*)d_in[3];
    const float* bhh0 = (const float*)d_in[4];
    const float* Wih1 = (const float*)d_in[5];
    const float* Whh1 = (const float*)d_in[6];
    const float* bih1 = (const float*)d_in[7];
    const float* bhh1 = (const float*)d_in[8];
    const float* Wfc  = (const float*)d_in[9];
    const float* bfc  = (const float*)d_in[10];
    float* out = (float*)d_out;

    // workspace (~45.2 MB total — identical envelope to rounds 1/2/4)
    char* p = (char*)d_ws;
    float* c0  = (float*)p; p += (size_t)B_ * H_ * 4;                       // 256 KB
    float* c1  = (float*)p; p += (size_t)B_ * H_ * 4;                       // 256 KB
    bf16* h0w  = (bf16*)p;  p += (size_t)2 * (CH_ + 1) * B_ * H_ * 2;       // 8.25 MB
    bf16* h1w  = (bf16*)p;  p += (size_t)(CH_ + 1) * B_ * H_ * 2;           // 4.13 MB
    bf16* xg0  = (bf16*)p;  p += (size_t)CH_ * B_ * G4H * 2;                // 16 MB
    bf16* xg1  = (bf16*)p;  p += (size_t)CH_ * B_ * G4H * 2;                // 16 MB
    unsigned* bar = (unsigned*)p;
    const int nbar = 2 * CH_ * LSTR * BARSTR;                               // 64 KB, reused
    p += (size_t)nbar * 4;

    init_k<<<(B_ * H_ + 255) / 256, 256, 0, stream>>>(c0, c1, h0w, h1w, bar, nbar);

    const dim3 gxg0((B_ * CH_) / 128, G4H / 128);  // 16 x 32
    const dim3 gfc((B_ * CH_) / 128, O_ / 128);    // 16 x 4

    // Diagonal pipeline over 17 groups: layer0 on chunk c, layer1 on chunk c-1.
    for (int c = 0; c <= NCH; c++) {
        const int do0 = (c < NCH);
        const int do1 = (c >= 1);

        if (do0) {
            // xg0(c): xg0[t][b] = x[b][c*CH+t] @ Wih0^T + bih0 + bhh0   (A fp32)
            gemm_bt<1, 0, 0, bf16><<<gxg0, 256, 0, stream>>>(
                x, Wih0, xg0, bih0, bhh0, B_ * CH_, G4H, I_, c * CH_);
        }
        if (do1) {
            // xg1(c-1): from h0 window buf (c-1)&1, slots 1..CH           (A bf16)
            const bf16* h0chunk = h0w + (size_t)((c - 1) & 1) * (CH_ + 1) * B_ * H_ + B_ * H_;
            gemm_bt<0, 0, 1, bf16><<<gxg0, 256, 0, stream>>>(
                h0chunk, Wih1, xg1, bih1, bhh1, B_ * CH_, G4H, H_, 0);
        }

        // one persistent cooperative launch = all CH_ steps of this group
        {
            const bf16*  a0  = xg0;  const bf16*  a1  = xg1;
            const float* w0  = Whh0; const float* w1  = Whh1;
            bf16* hp0 = h0w; bf16* hp1 = h1w;
            float* cp0 = c0; float* cp1 = c1;
            unsigned* bp = bar;
            int cv = c, d0 = do0, d1 = do1;
            void* args[] = { &a0, &a1, &w0, &w1, &hp0, &hp1,
                             &cp0, &cp1, &bp, &cv, &d0, &d1 };
            hipLaunchCooperativeKernel((const void*)chunk_k,
                                       dim3(NBLK), dim3(THR_), args, 0, stream);
        }

        if (do1) {
            // FC on layer-1 chunk c-1: out rows t0=(c-1)*CH              (A bf16, C fp32)
            gemm_bt<0, 2, 1, float><<<gfc, 256, 0, stream>>>(
                h1w + B_ * H_, Wfc, out, bfc, (const float*)nullptr,
                B_ * CH_, O_, H_, (c - 1) * CH_);
        }
    }

    finalize_k<<<(B_ * H_ + 255) / 256, 256, 0, stream>>>(
        h0w, h1w, c0, c1,
        out + (size_t)B_ * S_ * O_,
        out + (size_t)B_ * S_ * O_ + 2 * (size_t)B_ * H_);
}

// Round 6
// 8125.161 us; speedup vs baseline: 3.8429x; 1.0019x over previous
//
#include <hip/hip_runtime.h>
#include <hip/hip_bf16.h>

#define B_   64
#define S_   512
#define I_   512
#define H_   1024
#define G4H  4096
#define O_   512
#define CH_  32    // timesteps per chunk
#define NCH  (S_ / CH_)   // 16 chunks per layer

#define NBLK   128        // chunk_k grid: 64 blocks/layer (16 hidden units each)
#define THR_   512        // threads per chunk_k block (8 waves)
#define LSTR   8          // barrier stripes per layer
#define BARSTR 32         // uints per stripe (128B, own cacheline)

typedef short s16x8 __attribute__((ext_vector_type(8)));
typedef short s16x4 __attribute__((ext_vector_type(4)));
typedef float f32x4 __attribute__((ext_vector_type(4)));
typedef unsigned long long u64;
using bf16 = __hip_bfloat16;

__device__ __forceinline__ float bf2f(bf16 v) { return __bfloat162float(v); }
__device__ __forceinline__ bf16  f2bf(float f) { return __float2bfloat16(f); }
__device__ __forceinline__ short f2bfb(float f) { bf16 h = __float2bfloat16(f); return *(short*)&h; }

__device__ __forceinline__ void storeC(float* p, float v) { *p = v; }
__device__ __forceinline__ void storeC(bf16* p, float v)  { *p = f2bf(v); }

// ---------------------------------------------------------------------------
// C = A @ Bw^T (+bias1+bias2). Bw fp32 global (bf16-converted while staging).
// Tile 128x128, BK=32, 256 threads (4 waves, 64x64 quadrant each).
// ---------------------------------------------------------------------------
template <int AMAP, int CMAP, int ABF, typename CT>
__global__ __launch_bounds__(256) void gemm_bt(
    const void* __restrict__ Av, const float* __restrict__ Bw,
    CT* __restrict__ C,
    const float* __restrict__ bias1, const float* __restrict__ bias2,
    int M, int N, int K, int t0)
{
    __shared__ bf16 As[128 * 40];
    __shared__ bf16 Bs[128 * 40];

    const int tid  = threadIdx.x;
    const int wave = tid >> 6;
    const int lane = tid & 63;
    const int quad = lane >> 4;
    const int l16  = lane & 15;

    const int m_base = blockIdx.x * 128;
    const int n_base = blockIdx.y * 128;
    const int wm = (wave >> 1) * 64;
    const int wn = (wave & 1) * 64;

    f32x4 acc[4][4] = {};

    for (int k0 = 0; k0 < K; k0 += 32) {
        __syncthreads();
#pragma unroll
        for (int i = 0; i < 2; i++) {
            int l   = tid + i * 256;     // 0..511
            int row = l >> 2;            // 0..127
            int ko  = (l & 3) * 8;       // 0,8,16,24
            int m   = m_base + row;
            long ar = m;
            if (AMAP == 1) ar = (long)(m & 63) * S_ + t0 + (m >> 6);

            if (ABF) {
                const bf16* ap = (const bf16*)Av + ar * (long)K + k0 + ko;
                *(s16x8*)(&As[row * 40 + ko]) = *(const s16x8*)ap;
            } else {
                const float* ap = (const float*)Av + ar * (long)K + k0 + ko;
                f32x4 a0 = *(const f32x4*)ap;
                f32x4 a1 = *(const f32x4*)(ap + 4);
                s16x8 av;
#pragma unroll
                for (int j = 0; j < 4; j++) { av[j] = f2bfb(a0[j]); av[4 + j] = f2bfb(a1[j]); }
                *(s16x8*)(&As[row * 40 + ko]) = av;
            }

            const float* bp = &Bw[(long)(n_base + row) * K + k0 + ko];
            f32x4 b0 = *(const f32x4*)bp;
            f32x4 b1 = *(const f32x4*)(bp + 4);
            s16x8 bv;
#pragma unroll
            for (int j = 0; j < 4; j++) { bv[j] = f2bfb(b0[j]); bv[4 + j] = f2bfb(b1[j]); }
            *(s16x8*)(&Bs[row * 40 + ko]) = bv;
        }
        __syncthreads();

        s16x8 af[4], bfr[4];
#pragma unroll
        for (int i = 0; i < 4; i++)
            af[i] = *(const s16x8*)(&As[(wm + i * 16 + l16) * 40 + quad * 8]);
#pragma unroll
        for (int j = 0; j < 4; j++)
            bfr[j] = *(const s16x8*)(&Bs[(wn + j * 16 + l16) * 40 + quad * 8]);
#pragma unroll
        for (int i = 0; i < 4; i++)
#pragma unroll
            for (int j = 0; j < 4; j++)
                acc[i][j] = __builtin_amdgcn_mfma_f32_16x16x32_bf16(af[i], bfr[j], acc[i][j], 0, 0, 0);
    }

    // C/D layout: col = lane&15, row = (lane>>4)*4 + reg
#pragma unroll
    for (int i = 0; i < 4; i++) {
#pragma unroll
        for (int j = 0; j < 4; j++) {
#pragma unroll
            for (int r = 0; r < 4; r++) {
                int m = m_base + wm + i * 16 + quad * 4 + r;
                int n = n_base + wn + j * 16 + l16;
                float v = acc[i][j][r];
                if (bias1) v += bias1[n];
                if (bias2) v += bias2[n];
                long cr = m;
                if (CMAP == 2) cr = (long)(m & 63) * S_ + t0 + (m >> 6);
                storeC(&C[cr * (long)N + n], v);
            }
        }
    }
}

// ---------------------------------------------------------------------------
// Per-layer striped fence-free barrier. Domain = the 64 blocks of one layer.
// 8 stripes/layer, one cacheline each; block (bid&63)&7 RMWs its stripe
// (8 arrivals/line); lanes 0..7 poll the 8 stripes concurrently. Counters
// monotonic, REUSED across the 17 sequential launches via per-layer targets.
// Cross-block data moves via agent-scope relaxed atomics (sc1, coherent
// point) -> no cache-maintenance fences; __syncthreads before the arrive
// drains the wave's sc1 stores (vmcnt ack).
// ---------------------------------------------------------------------------
__device__ __forceinline__ void grid_bar(unsigned* ctr, unsigned target)
{
    __syncthreads();
    const int t = threadIdx.x;
    if (t == 0)
        __hip_atomic_fetch_add(ctr + ((blockIdx.x & 63) & (LSTR - 1)) * BARSTR, 1u,
                               __ATOMIC_RELAXED, __HIP_MEMORY_SCOPE_AGENT);
    if (t < LSTR) {
        while (__hip_atomic_load(ctr + t * BARSTR, __ATOMIC_RELAXED,
                                 __HIP_MEMORY_SCOPE_AGENT) < target)
            __builtin_amdgcn_s_sleep(1);
    }
    __syncthreads();
}

// ---------------------------------------------------------------------------
// Persistent per-chunk recurrence. 128 blocks: [0,64) layer 0 (iff do0),
// [64,128) layer 1 (iff do1); inactive blocks return (per-layer barriers).
// Each block owns 16 hidden units = 64 gate-cols. Whh slice (64 x 1024)
// staged fp32->bf16 into 132 KB LDS once per chunk. 8 waves = (kw, mw):
// wave loads rows mw*16+l16 over K-half kw (16x 16B-equivalent sc1 loads)
// and runs 64 MFMA (4 col-frags x 16 k-steps). K-half partials merge via a
// two-phase LDS accumulate (kw0 writes gs, sync, kw1 adds). xg for step j+1
// prefetched into registers before the barrier wait. c-state in registers.
// ---------------------------------------------------------------------------
__global__ __launch_bounds__(THR_, 1) void chunk_k(
    const bf16* __restrict__ xg0,  // [CH][B][4H] layer-0 input contrib, chunk cpar
    const bf16* __restrict__ xg1,  // [CH][B][4H] layer-1 input contrib, chunk cpar-1
    const float* __restrict__ Whh0,
    const float* __restrict__ Whh1,
    bf16* __restrict__ h0w,        // [2][CH+1][B][H] double-buffered window
    bf16* __restrict__ h1w,        // [CH+1][B][H]
    float* __restrict__ c0,
    float* __restrict__ c1,
    unsigned* __restrict__ bar,    // [2][CH][LSTR][BARSTR], zeroed once, reused
    int cpar, int do0, int do1)
{
    const int layer  = blockIdx.x >> 6;
    const int nb     = blockIdx.x & 63;
    const int active = layer ? do1 : do0;   // block-uniform
    if (!active) return;

    const bf16*  xg  = layer ? xg1  : xg0;
    const float* Whh = layer ? Whh1 : Whh0;
    float*       cst = layer ? c1   : c0;

    bf16 *rbuf, *cbuf;
    if (layer == 0) {
        rbuf = h0w + (size_t)(cpar & 1) * (CH_ + 1) * B_ * H_;
        cbuf = h0w + (size_t)((cpar + 1) & 1) * (CH_ + 1) * B_ * H_;
    } else {
        rbuf = h1w; cbuf = h1w;
    }

    const int tid  = threadIdx.x;
    const int lane = tid & 63;
    const int wave = tid >> 6;     // 0..7
    const int quad = lane >> 4;
    const int l16  = lane & 15;
    const int kw   = wave >> 2;    // K-half (0: k<512, 1: k>=512)
    const int mw   = wave & 3;     // row-group (rows mw*16 + l16)

    // per-layer barrier region + monotonic reuse target
    unsigned* barL = bar + (size_t)layer * CH_ * LSTR * BARSTR;
    const unsigned bar_tgt =
        (layer ? (unsigned)cpar : (unsigned)(cpar + 1)) * (64 / LSTR);

    __shared__ bf16  wsh[64][1032];   // 132.1 KB; +8 pad: 2-way aliasing only
    __shared__ float gs[64][68];      // 17.4 KB; [batch][gate-col]

    // stage Whh slice (64 gate-rows x 1024) fp32 -> bf16 LDS, ONCE per chunk.
    // wsh row r: gate g = r>>4, unit uu = r&15 -> Whh row g*H + nb*16 + uu
    {
        int r  = tid >> 3;                 // 0..63
        int cc = (tid & 7) * 128;          // 128 elems per thread
        const float* src = Whh + ((long)(r >> 4) * H_ + nb * 16 + (r & 15)) * H_ + cc;
#pragma unroll
        for (int q = 0; q < 128; q += 4) {
            f32x4 v = *(const f32x4*)(src + q);
            s16x4 o;
#pragma unroll
            for (int w = 0; w < 4; w++) o[w] = f2bfb(v[w]);
            *(s16x4*)(&wsh[r][cc + q]) = o;
        }
    }
    __syncthreads();

    // epilogue cell ownership: 1024 cells (64 batches x 16 units), 2/thread
    // cell = tid + rep*512: bb = cell>>4, uu = cell&15
    const int uu   = tid & 15;
    const int unit = nb * 16 + uu;
    float creg[2];
#pragma unroll
    for (int rep = 0; rep < 2; rep++) {
        int bb = (tid + rep * 512) >> 4;
        creg[rep] = cst[(long)bb * H_ + unit];
    }

    // prologue: xg prefetch for j=0
    float xn[2][4];
#pragma unroll
    for (int rep = 0; rep < 2; rep++) {
        int bb = (tid + rep * 512) >> 4;
#pragma unroll
        for (int g = 0; g < 4; g++)
            xn[rep][g] = bf2f(xg[(long)bb * G4H + (long)g * H_ + unit]);
    }

    for (int j = 0; j < CH_; j++) {
        // ---- MFMA phase: rows mw*16+l16, K-half kw, all 64 gate-cols ----
        const u64* ap = (const u64*)(rbuf + (long)j * (B_ * H_)
                       + (long)(mw * 16 + l16) * H_ + kw * 512) + quad * 2;
        u64 la[16], lb[16];
#pragma unroll
        for (int t = 0; t < 16; t++) {
            u64* p = (u64*)(ap + (size_t)t * 8);
            la[t] = __hip_atomic_load(p,     __ATOMIC_RELAXED, __HIP_MEMORY_SCOPE_AGENT);
            lb[t] = __hip_atomic_load(p + 1, __ATOMIC_RELAXED, __HIP_MEMORY_SCOPE_AGENT);
        }

        f32x4 acc[4] = {};
#pragma unroll
        for (int t = 0; t < 16; t++) {
            union { u64 q[2]; s16x8 v; } ua;
            ua.q[0] = la[t]; ua.q[1] = lb[t];
            int k = kw * 512 + t * 32;
#pragma unroll
            for (int cf = 0; cf < 4; cf++) {
                s16x8 b = *(const s16x8*)(&wsh[cf * 16 + l16][k + quad * 8]);
                acc[cf] = __builtin_amdgcn_mfma_f32_16x16x32_bf16(ua.v, b, acc[cf], 0, 0, 0);
            }
        }

        // ---- two-phase K-half merge in gs ----
        // C layout: col = cf*16 + l16, row = mw*16 + quad*4 + r
        if (kw == 0) {
#pragma unroll
            for (int cf = 0; cf < 4; cf++)
#pragma unroll
                for (int r = 0; r < 4; r++)
                    gs[mw * 16 + quad * 4 + r][cf * 16 + l16] = acc[cf][r];
        }
        __syncthreads();
        if (kw == 1) {
#pragma unroll
            for (int cf = 0; cf < 4; cf++)
#pragma unroll
                for (int r = 0; r < 4; r++)
                    gs[mw * 16 + quad * 4 + r][cf * 16 + l16] += acc[cf][r];
        }
        __syncthreads();

        // ---- epilogue: gates + state update + h-store ----
        unsigned short hb[2];
#pragma unroll
        for (int rep = 0; rep < 2; rep++) {
            int bb = (tid + rep * 512) >> 4;
            float gi = gs[bb][uu]      + xn[rep][0];
            float gf = gs[bb][16 + uu] + xn[rep][1];
            float gg = gs[bb][32 + uu] + xn[rep][2];
            float go = gs[bb][48 + uu] + xn[rep][3];

            float ig = 1.f / (1.f + __expf(-gi));
            float fg = 1.f / (1.f + __expf(-gf));
            float og = 1.f / (1.f + __expf(-go));
            float e2 = __expf(-2.f * fabsf(gg));
            float tg = (1.f - e2) / (1.f + e2);
            tg = (gg < 0.f) ? -tg : tg;

            creg[rep] = fg * creg[rep] + ig * tg;
            float e2c = __expf(-2.f * fabsf(creg[rep]));
            float tc = (1.f - e2c) / (1.f + e2c);
            tc = (creg[rep] < 0.f) ? -tc : tc;

            bf16 hv = f2bf(og * tc);
            hb[rep] = *(unsigned short*)&hv;
        }
        // pair adjacent units via shfl -> 4B agent-relaxed stores
#pragma unroll
        for (int rep = 0; rep < 2; rep++) {
            int bb = (tid + rep * 512) >> 4;
            unsigned my    = hb[rep];
            unsigned other = (unsigned)__shfl((int)my, lane ^ 1, 64);
            if (!(uu & 1)) {
                unsigned v32 = my | (other << 16);
                unsigned* dst = (unsigned*)(rbuf + (long)(j + 1) * (B_ * H_)
                                + (long)bb * H_ + unit);
                __hip_atomic_store(dst, v32, __ATOMIC_RELAXED, __HIP_MEMORY_SCOPE_AGENT);
                if (j == CH_ - 1) {
                    unsigned* cd = (unsigned*)(cbuf + (long)bb * H_ + unit);
                    __hip_atomic_store(cd, v32, __ATOMIC_RELAXED, __HIP_MEMORY_SCOPE_AGENT);
                }
            }
        }

        // prefetch next step's xg (launch-constant; hides under barrier wait)
        if (j + 1 < CH_) {
            const bf16* xq = xg + (long)(j + 1) * (B_ * G4H);
#pragma unroll
            for (int rep = 0; rep < 2; rep++) {
                int bb = (tid + rep * 512) >> 4;
#pragma unroll
                for (int g = 0; g < 4; g++)
                    xn[rep][g] = bf2f(xq[(long)bb * G4H + (long)g * H_ + unit]);
            }
        }

        // inter-step per-layer barrier (skip after last step)
        if (j < CH_ - 1)
            grid_bar(barL + (size_t)j * LSTR * BARSTR, bar_tgt);
    }

#pragma unroll
    for (int rep = 0; rep < 2; rep++) {
        int bb = (tid + rep * 512) >> 4;
        cst[(long)bb * H_ + unit] = creg[rep];
    }
}

// zero c-states, carry-in h slots, and barrier counters
__global__ __launch_bounds__(256) void init_k(
    float* c0, float* c1, bf16* h0w, bf16* h1w, unsigned* bar, int nbar)
{
    int i = blockIdx.x * 256 + threadIdx.x;
    if (i < B_ * H_) {
        c0[i] = 0.f; c1[i] = 0.f;
        h0w[i] = f2bf(0.f);   // buf 0, slot 0
        h1w[i] = f2bf(0.f);   // slot 0
    }
    if (i < nbar) bar[i] = 0u;
}

// h_n: layer0 = h0w buf0 slot0 (final carry), layer1 = h1w slot0. c_n fp32.
__global__ __launch_bounds__(256) void finalize_k(
    const bf16* __restrict__ h0w, const bf16* __restrict__ h1w,
    const float* __restrict__ c0, const float* __restrict__ c1,
    float* __restrict__ out_hn, float* __restrict__ out_cn)
{
    int i = blockIdx.x * 256 + threadIdx.x;
    if (i < B_ * H_) {
        out_hn[i]            = bf2f(h0w[i]);
        out_hn[B_ * H_ + i]  = bf2f(h1w[i]);
        out_cn[i]            = c0[i];
        out_cn[B_ * H_ + i]  = c1[i];
    }
}

extern "C" void kernel_launch(void* const* d_in, const int* in_sizes, int n_in,
                              void* d_out, int out_size, void* d_ws, size_t ws_size,
                              hipStream_t stream)
{
    const float* x    = (const float*)d_in[0];
    const float* Wih0 = (const float*)d_in[1];
    const float* Whh0 = (const float*)d_in[2];
    const float* bih0 = (const float*)d_in[3];
    const float* bhh0 = (const float*)d_in[4];
    const float* Wih1 = (const float*)d_in[5];
    const float* Whh1 = (const float*)d_in[6];
    const float* bih1 = (const float*)d_in[7];
    const float* bhh1 = (const float*)d_in[8];
    const float* Wfc  = (const float*)d_in[9];
    const float* bfc  = (const float*)d_in[10];
    float* out = (float*)d_out;

    // workspace (~45.2 MB total — identical envelope to rounds 1/2/4/5)
    char* p = (char*)d_ws;
    float* c0  = (float*)p; p += (size_t)B_ * H_ * 4;                       // 256 KB
    float* c1  = (float*)p; p += (size_t)B_ * H_ * 4;                       // 256 KB
    bf16* h0w  = (bf16*)p;  p += (size_t)2 * (CH_ + 1) * B_ * H_ * 2;       // 8.25 MB
    bf16* h1w  = (bf16*)p;  p += (size_t)(CH_ + 1) * B_ * H_ * 2;           // 4.13 MB
    bf16* xg0  = (bf16*)p;  p += (size_t)CH_ * B_ * G4H * 2;                // 16 MB
    bf16* xg1  = (bf16*)p;  p += (size_t)CH_ * B_ * G4H * 2;                // 16 MB
    unsigned* bar = (unsigned*)p;
    const int nbar = 2 * CH_ * LSTR * BARSTR;                               // 64 KB, reused
    p += (size_t)nbar * 4;

    init_k<<<(B_ * H_ + 255) / 256, 256, 0, stream>>>(c0, c1, h0w, h1w, bar, nbar);

    const dim3 gxg0((B_ * CH_) / 128, G4H / 128);  // 16 x 32
    const dim3 gfc((B_ * CH_) / 128, O_ / 128);    // 16 x 4

    // Diagonal pipeline over 17 groups: layer0 on chunk c, layer1 on chunk c-1.
    for (int c = 0; c <= NCH; c++) {
        const int do0 = (c < NCH);
        const int do1 = (c >= 1);

        if (do0) {
            // xg0(c): xg0[t][b] = x[b][c*CH+t] @ Wih0^T + bih0 + bhh0   (A fp32)
            gemm_bt<1, 0, 0, bf16><<<gxg0, 256, 0, stream>>>(
                x, Wih0, xg0, bih0, bhh0, B_ * CH_, G4H, I_, c * CH_);
        }
        if (do1) {
            // xg1(c-1): from h0 window buf (c-1)&1, slots 1..CH           (A bf16)
            const bf16* h0chunk = h0w + (size_t)((c - 1) & 1) * (CH_ + 1) * B_ * H_ + B_ * H_;
            gemm_bt<0, 0, 1, bf16><<<gxg0, 256, 0, stream>>>(
                h0chunk, Wih1, xg1, bih1, bhh1, B_ * CH_, G4H, H_, 0);
        }

        // one persistent cooperative launch = all CH_ steps of this group
        {
            const bf16*  a0  = xg0;  const bf16*  a1  = xg1;
            const float* w0  = Whh0; const float* w1  = Whh1;
            bf16* hp0 = h0w; bf16* hp1 = h1w;
            float* cp0 = c0; float* cp1 = c1;
            unsigned* bp = bar;
            int cv = c, d0 = do0, d1 = do1;
            void* args[] = { &a0, &a1, &w0, &w1, &hp0, &hp1,
                             &cp0, &cp1, &bp, &cv, &d0, &d1 };
            hipLaunchCooperativeKernel((const void*)chunk_k,
                                       dim3(NBLK), dim3(THR_), args, 0, stream);
        }

        if (do1) {
            // FC on layer-1 chunk c-1: out rows t0=(c-1)*CH              (A bf16, C fp32)
            gemm_bt<0, 2, 1, float><<<gfc, 256, 0, stream>>>(
                h1w + B_ * H_, Wfc, out, bfc, (const float*)nullptr,
                B_ * CH_, O_, H_, (c - 1) * CH_);
        }
    }

    finalize_k<<<(B_ * H_ + 255) / 256, 256, 0, stream>>>(
        h0w, h1w, c0, c1,
        out + (size_t)B_ * S_ * O_,
        out + (size_t)B_ * S_ * O_ + 2 * (size_t)B_ * H_);
}